// Round 15
// baseline (1128.882 us; speedup 1.0000x reference)
//
#include <hip/hip_runtime.h>
#include <hip/hip_bf16.h>
#include <math.h>

#define B_ 2
#define S_ 1024
#define V_ 32000
#define D_ 768
#define F_ 3072
#define H_ 12
#define L_ 6
#define DH_ 64
#define BS_ (B_*S_)   // 2048
#define NQKV_ 2304
#define KVB_ 64

typedef __attribute__((ext_vector_type(8))) short short8;
typedef __attribute__((ext_vector_type(4))) float f32x4;

__device__ __forceinline__ unsigned short f2b(float f) {
    union { __hip_bfloat16 h; unsigned short u; } cv;
    cv.h = __float2bfloat16(f);
    return cv.u;
}

__device__ __forceinline__ float b2f(unsigned short u) {
    union { unsigned int i; float f; } cv;
    cv.i = ((unsigned int)u) << 16;
    return cv.f;
}

__device__ __forceinline__ void store_bf4(__hip_bfloat16* p, float a, float b, float c, float d) {
    unsigned long long pk = (unsigned long long)f2b(a)
        | ((unsigned long long)f2b(b) << 16)
        | ((unsigned long long)f2b(c) << 32)
        | ((unsigned long long)f2b(d) << 48);
    *(unsigned long long*)p = pk;
}

__device__ __forceinline__ void gld16(const void* g, void* l) {
    __builtin_amdgcn_global_load_lds(
        (const __attribute__((address_space(1))) unsigned int*)g,
        (__attribute__((address_space(3))) unsigned int*)l,
        16, 0, 0);
}

// ---------------- embedding (dual write f32 + bf16) ----------------
__global__ void embed_k(const int* __restrict__ x, const float* __restrict__ tok,
                        const float* __restrict__ pos, float* __restrict__ h,
                        __hip_bfloat16* __restrict__ hbf) {
    int bs = blockIdx.x;
    int s = bs % S_;
    int t = x[bs];
    for (int d = threadIdx.x; d < D_; d += blockDim.x) {
        float v = tok[(size_t)t * D_ + d] + pos[(size_t)s * D_ + d];
        h[(size_t)bs * D_ + d] = v;
        hbf[(size_t)bs * D_ + d] = __float2bfloat16(v);
    }
}

// ---------------- transpose+convert: src f32 [K][N] -> dst bf16 [N][K] ----------------
__global__ __launch_bounds__(256) void transp_k(const float* __restrict__ src, size_t sl,
                                                __hip_bfloat16* __restrict__ dst, size_t dl,
                                                int N, int K) {
    const float* S = src + (size_t)blockIdx.z * sl;
    __hip_bfloat16* Dp = dst + (size_t)blockIdx.z * dl;
    __shared__ float T[32][33];
    const int k0 = blockIdx.y * 32, n0 = blockIdx.x * 32;
    const int tid = threadIdx.x;
    const int r = tid >> 3, c4 = (tid & 7) * 4;
    float4 vv = *(const float4*)&S[(size_t)(k0 + r) * N + n0 + c4];
    T[r][c4 + 0] = vv.x; T[r][c4 + 1] = vv.y; T[r][c4 + 2] = vv.z; T[r][c4 + 3] = vv.w;
    __syncthreads();
    store_bf4(&Dp[(size_t)(n0 + r) * K + k0 + c4],
              T[c4 + 0][r], T[c4 + 1][r], T[c4 + 2][r], T[c4 + 3][r]);
}

// ---------------- concat qkv biases ----------------
__global__ void bcat_k(const float* __restrict__ bq, const float* __restrict__ bk,
                       const float* __restrict__ bv, float* __restrict__ dst) {
    int l = blockIdx.x;
    for (int j = threadIdx.x; j < D_; j += blockDim.x) {
        dst[(size_t)l * NQKV_ + j]          = bq[(size_t)l * D_ + j];
        dst[(size_t)l * NQKV_ + D_ + j]     = bk[(size_t)l * D_ + j];
        dst[(size_t)l * NQKV_ + 2 * D_ + j] = bv[(size_t)l * D_ + j];
    }
}

// ---------------- MFMA bf16 GEMM: C = act(A[M,K] @ Bt[N,K]^T + bias) ----------------
// LDS tiles XOR-swizzled (T2): pre-swizzled global source chunks (linear gld16
// dest), fragment read byte ^= (row&7)<<4. SW: M on blockIdx.x. XS: XCD-bijective
// block swizzle. WVT: QKV mode -- V-cols written to vT[bh][d][s], Q-cols
// pre-scaled by 1/sqrt(768). ldcb = bf16 C row stride.
template<int BM, int BN, int ACT, bool WF32, bool WBF, bool SW, bool XS, bool WVT>
__global__ __launch_bounds__(256) void mgemm_k(const __hip_bfloat16* __restrict__ A,
                                               const __hip_bfloat16* __restrict__ Bt,
                                               const float* __restrict__ bias,
                                               float* __restrict__ Cf,
                                               __hip_bfloat16* __restrict__ Cb,
                                               __hip_bfloat16* __restrict__ vTp,
                                               int M, int N, int K, int ldcb) {
    constexpr int WM = BM / 2, WN = BN / 2;
    constexpr int FM = WM / 16, FN = WN / 16;
    __shared__ __hip_bfloat16 Al[BM * 64];
    __shared__ __hip_bfloat16 Bl[BN * 64];
    const int tid = threadIdx.x;
    const int wid = tid >> 6, lane = tid & 63;
    const int wr = wid >> 1, wc = wid & 1;
    const int lrow = lane & 15, kq = lane >> 4;

    int bx = blockIdx.x, by = blockIdx.y;
    if (XS) {
        const int gx = gridDim.x;
        const int nwg = gx * gridDim.y;
        const int lin = by * gx + bx;
        const int logical = (lin & 7) * (nwg >> 3) + (lin >> 3);
        bx = logical % gx;
        by = logical / gx;
    }
    const int row0 = (SW ? bx : by) * BM;
    const int col0 = (SW ? by : bx) * BN;

    f32x4 acc[FM][FN];
    #pragma unroll
    for (int i = 0; i < FM; ++i)
        #pragma unroll
        for (int j = 0; j < FN; ++j)
            acc[i][j] = (f32x4){0.f, 0.f, 0.f, 0.f};

    const int srow = (lane >> 3);
    const int scol = ((lane & 7) ^ srow) * 8;   // pre-swizzled source chunk (T21)

    for (int kk = 0; kk < K; kk += 64) {
        #pragma unroll
        for (int i = 0; i < BM / 32; ++i)
            gld16(A + (size_t)(row0 + i * 32 + wid * 8 + srow) * K + kk + scol,
                  &Al[(i * 32 + wid * 8) * 64]);
        #pragma unroll
        for (int i = 0; i < BN / 32; ++i)
            gld16(Bt + (size_t)(col0 + i * 32 + wid * 8 + srow) * K + kk + scol,
                  &Bl[(i * 32 + wid * 8) * 64]);
        __syncthreads();

        #pragma unroll
        for (int kc = 0; kc < 2; ++kc) {
            short8 af[FM], bfr[FN];
            #pragma unroll
            for (int i = 0; i < FM; ++i) {
                const int row = wr * WM + i * 16 + lrow;
                af[i] = *(const short8*)((const char*)Al + row * 128
                          + ((kc * 64 + kq * 16) ^ ((row & 7) << 4)));
            }
            #pragma unroll
            for (int j = 0; j < FN; ++j) {
                const int row = wc * WN + j * 16 + lrow;
                bfr[j] = *(const short8*)((const char*)Bl + row * 128
                          + ((kc * 64 + kq * 16) ^ ((row & 7) << 4)));
            }
            #pragma unroll
            for (int i = 0; i < FM; ++i)
                #pragma unroll
                for (int j = 0; j < FN; ++j)
                    acc[i][j] = __builtin_amdgcn_mfma_f32_16x16x32_bf16(af[i], bfr[j], acc[i][j], 0, 0, 0);
        }
        __syncthreads();
    }

    #pragma unroll
    for (int i = 0; i < FM; ++i)
        #pragma unroll
        for (int j = 0; j < FN; ++j) {
            const int col = col0 + wc * WN + j * 16 + lrow;
            const float bv = bias[col];
            const int rowq = row0 + wr * WM + i * 16 + kq * 4;
            if (WVT && col >= 1536) {
                const int cv = col - 1536;
                const int bh = (rowq >> 10) * H_ + (cv >> 6);
                store_bf4(&vTp[((size_t)bh * DH_ + (cv & 63)) * S_ + (rowq & 1023)],
                          acc[i][j][0] + bv, acc[i][j][1] + bv,
                          acc[i][j][2] + bv, acc[i][j][3] + bv);
            } else {
                #pragma unroll
                for (int r = 0; r < 4; ++r) {
                    const int row = rowq + r;
                    float vv = acc[i][j][r] + bv;
                    if (ACT == 1) vv = 0.5f * vv * (1.0f + erff(vv * 0.70710678118654752f));
                    if (WVT && col < D_) vv *= 0.03608439182435161f;  // fold attn scale into Q
                    if (WF32) Cf[(size_t)row * N + col] = vv;
                    if (WBF)  Cb[(size_t)row * ldcb + col] = __float2bfloat16(vv);
                }
            }
        }
}

// ---------------- legacy f32 GEMM (fallback for logits if no workspace) ----------------
__global__ __launch_bounds__(256) void gemm_k(const float* __restrict__ A,
                                              const float* __restrict__ W,
                                              const float* __restrict__ bias,
                                              float* __restrict__ Cout,
                                              int M, int N, int K) {
    __shared__ float As[64][16];
    __shared__ float Bs[16][64];
    const int tid = threadIdx.x;
    const int tx = tid & 15, ty = tid >> 4;
    const int row0 = blockIdx.y * 64, col0 = blockIdx.x * 64;
    float acc[4][4] = {};

    for (int kk = 0; kk < K; kk += 16) {
        #pragma unroll
        for (int it = 0; it < 4; ++it) {
            int idx = tid + it * 256;
            int m = idx >> 4, k = idx & 15;
            As[m][k] = A[(size_t)(row0 + m) * K + kk + k];
            int r = idx >> 6, c = idx & 63;
            Bs[r][c] = W[(size_t)(kk + r) * N + col0 + c];
        }
        __syncthreads();
        #pragma unroll
        for (int k = 0; k < 16; ++k) {
            float a[4], b[4];
            #pragma unroll
            for (int i = 0; i < 4; ++i) a[i] = As[ty * 4 + i][k];
            #pragma unroll
            for (int j = 0; j < 4; ++j) b[j] = Bs[k][tx * 4 + j];
            #pragma unroll
            for (int i = 0; i < 4; ++i)
                #pragma unroll
                for (int j = 0; j < 4; ++j)
                    acc[i][j] += a[i] * b[j];
        }
        __syncthreads();
    }

    #pragma unroll
    for (int i = 0; i < 4; ++i) {
        int r = row0 + ty * 4 + i;
        #pragma unroll
        for (int j = 0; j < 4; ++j) {
            int c = col0 + tx * 4 + j;
            Cout[(size_t)r * N + c] = acc[i][j] + bias[c];
        }
    }
}

// ---------------- MFMA flash attention, KV tile 64, double-buffered, 40 KB LDS ----------------
// 256 thr = 4 waves, 64 q-rows/block; KV tile 64 -> Ks/Vt/Ps rows are 128 B.
// 40 KB LDS -> 4 blocks/CU = 16 waves/CU (occupancy experiment vs KVB=128's 2 blocks).
// Swizzles: Ks byte^=(((r&7)^((r>>3)&7))<<4); Vt/Ps byte^=((row&7)<<4).
__global__ __launch_bounds__(256) void fattn_k(const __hip_bfloat16* __restrict__ qkv,
                                               const __hip_bfloat16* __restrict__ vT,
                                               __hip_bfloat16* __restrict__ o) {
    const int qt0 = blockIdx.x * 64;
    const int bh = blockIdx.y;
    const int b = bh / H_, hh = bh % H_;
    const size_t rb = (size_t)b * S_;
    const int hoff = hh * DH_;

    __shared__ __hip_bfloat16 Ks[2][KVB_ * 64];   // 2 x 8 KB
    __shared__ __hip_bfloat16 Vt[2][64 * KVB_];   // 2 x 8 KB
    __shared__ __hip_bfloat16 Ps[64 * KVB_];      // 8 KB

    const int tid = threadIdx.x;
    const int w = tid >> 6, lane = tid & 63;
    const int lr = lane & 15, lk = lane >> 4;
    const size_t vbase = (size_t)bh * DH_ * S_;

    short8 aq[2];
    {
        const int qrow = qt0 + w * 16 + lr;
        #pragma unroll
        for (int kc = 0; kc < 2; ++kc)
            aq[kc] = *(const short8*)&qkv[(rb + qrow) * NQKV_ + hoff + kc * 32 + lk * 8];
    }

    f32x4 oacc[4];
    float m_i[4], l_i[4];
    #pragma unroll
    for (int r = 0; r < 4; ++r) {
        oacc[r] = (f32x4){0.f, 0.f, 0.f, 0.f};
        m_i[r] = -1e30f;
        l_i[r] = 0.f;
    }

    auto stage = [&](int bi, int kt0) {
        // K [64 kv][64 d]: 16 rows/wave = 2 gld16 (8 rows each)
        #pragma unroll
        for (int t = 0; t < 2; ++t) {
            const int r0 = w * 16 + t * 8;
            const int r = r0 + (lane >> 3);
            const int cs = (lane & 7) ^ ((r & 7) ^ ((r >> 3) & 7));
            gld16(&qkv[(rb + kt0 + r) * NQKV_ + D_ + hoff + cs * 8], &Ks[bi][r0 * 64]);
        }
        // V^T [64 d][64 kv]: 16 rows/wave = 2 gld16
        #pragma unroll
        for (int t = 0; t < 2; ++t) {
            const int d0 = w * 16 + t * 8;
            const int d = d0 + (lane >> 3);
            const int cs = (lane & 7) ^ (d & 7);
            gld16(&vT[vbase + (size_t)d * S_ + kt0 + cs * 8], &Vt[bi][d0 * 64]);
        }
    };

    stage(0, 0);                                   // prologue
    int cur = 0;
    for (int kt0 = 0; kt0 < S_; kt0 += KVB_) {
        __syncthreads();                           // buf[cur] loads drained; prev compute done
        if (kt0 + KVB_ < S_) stage(cur ^ 1, kt0 + KVB_);   // overlap next-tile loads w/ compute
        const char* Kb = (const char*)Ks[cur];
        const char* Vb = (const char*)Vt[cur];

        // ---- scores S = Q @ K^T (Q pre-scaled in QKV epilogue) ----
        f32x4 s[4];
        #pragma unroll
        for (int j = 0; j < 4; ++j) s[j] = (f32x4){0.f, 0.f, 0.f, 0.f};
        __builtin_amdgcn_s_setprio(1);
        #pragma unroll
        for (int kc = 0; kc < 2; ++kc) {
            #pragma unroll
            for (int j = 0; j < 4; ++j) {
                int kr = j * 16 + lr;
                short8 bk = *(const short8*)(Kb + kr * 128
                              + ((kc * 64 + lk * 16) ^ ((((kr & 7) ^ ((kr >> 3) & 7)) << 4))));
                s[j] = __builtin_amdgcn_mfma_f32_16x16x32_bf16(aq[kc], bk, s[j], 0, 0, 0);
            }
        }
        __builtin_amdgcn_s_setprio(0);

        // ---- online softmax with defer-rescale (T13, THR=8) ----
        float tmax[4];
        #pragma unroll
        for (int r = 0; r < 4; ++r) {
            float t = s[0][r];
            #pragma unroll
            for (int j = 1; j < 4; ++j) t = fmaxf(t, s[j][r]);
            tmax[r] = t;
        }
        float excess = fmaxf(fmaxf(tmax[0] - m_i[0], tmax[1] - m_i[1]),
                             fmaxf(tmax[2] - m_i[2], tmax[3] - m_i[3]));
        if (!__all(excess <= 8.0f)) {
            #pragma unroll
            for (int r = 0; r < 4; ++r) {
                float tm = tmax[r];
                #pragma unroll
                for (int off = 1; off <= 8; off <<= 1)
                    tm = fmaxf(tm, __shfl_xor(tm, off));
                float mnew = fmaxf(m_i[r], tm);
                float corr = __expf(m_i[r] - mnew);
                m_i[r] = mnew;
                l_i[r] *= corr;
                #pragma unroll
                for (int jd = 0; jd < 4; ++jd) oacc[jd][r] *= corr;
            }
        }
        #pragma unroll
        for (int r = 0; r < 4; ++r) {
            float psum = 0.f;
            const int prow = w * 16 + lk * 4 + r;
            #pragma unroll
            for (int j = 0; j < 4; ++j) {
                float p = __expf(s[j][r] - m_i[r]);     // bounded by e^8
                psum += p;
                *(__hip_bfloat16*)((char*)Ps + prow * 128
                    + (((j * 16 + lr) * 2) ^ ((prow & 7) << 4))) = __float2bfloat16(p);
            }
            #pragma unroll
            for (int off = 1; off <= 8; off <<= 1)
                psum += __shfl_xor(psum, off);
            l_i[r] += psum;
        }

        // ---- PV: O += P @ V (Ps rows wave-private) ----
        __builtin_amdgcn_s_setprio(1);
        #pragma unroll
        for (int ks = 0; ks < 2; ++ks) {
            const int prow = w * 16 + lr;
            short8 pa = *(const short8*)((const char*)Ps + prow * 128
                          + ((ks * 64 + lk * 16) ^ ((prow & 7) << 4)));
            #pragma unroll
            for (int jd = 0; jd < 4; ++jd) {
                int vr = jd * 16 + lr;
                short8 vb = *(const short8*)(Vb + vr * 128
                              + ((ks * 64 + lk * 16) ^ ((vr & 7) << 4)));
                oacc[jd] = __builtin_amdgcn_mfma_f32_16x16x32_bf16(pa, vb, oacc[jd], 0, 0, 0);
            }
        }
        __builtin_amdgcn_s_setprio(0);
        cur ^= 1;
    }

    #pragma unroll
    for (int r = 0; r < 4; ++r) {
        float inv = 1.0f / l_i[r];
        const int row = qt0 + w * 16 + lk * 4 + r;
        #pragma unroll
        for (int jd = 0; jd < 4; ++jd)
            o[(rb + row) * (size_t)D_ + hoff + jd * 16 + lr] = __float2bfloat16(oacc[jd][r] * inv);
    }
}

// ---------------- add + layernorm; single-pass wave-reduce (1 barrier) ----------------
__global__ __launch_bounds__(256) void addln_k(const float* __restrict__ a,
                                               const float* __restrict__ b,
                                               const float* __restrict__ g,
                                               const float* __restrict__ beta,
                                               float* __restrict__ out,
                                               __hip_bfloat16* __restrict__ out_bf) {
    const int r = blockIdx.x;
    const int tid = threadIdx.x;
    const int wid = tid >> 6, lane = tid & 63;
    __shared__ float w1[4], w2[4];
    float xv[3];
    float s1 = 0.f, s2 = 0.f;
    #pragma unroll
    for (int i = 0; i < 3; ++i) {
        int d = tid + i * 256;
        xv[i] = a[(size_t)r * D_ + d] + b[(size_t)r * D_ + d];
        s1 += xv[i];
        s2 += xv[i] * xv[i];
    }
    #pragma unroll
    for (int off = 1; off <= 32; off <<= 1) {
        s1 += __shfl_xor(s1, off);
        s2 += __shfl_xor(s2, off);
    }
    if (lane == 0) { w1[wid] = s1; w2[wid] = s2; }
    __syncthreads();
    s1 = w1[0] + w1[1] + w1[2] + w1[3];
    s2 = w2[0] + w2[1] + w2[2] + w2[3];
    float mu = s1 * (1.0f / D_);
    float var = s2 * (1.0f / D_) - mu * mu;
    float rstd = rsqrtf(var + 1e-5f);
    #pragma unroll
    for (int i = 0; i < 3; ++i) {
        int d = tid + i * 256;
        float v = (xv[i] - mu) * rstd * g[d] + beta[d];
        out[(size_t)r * D_ + d] = v;
        out_bf[(size_t)r * D_ + d] = __float2bfloat16(v);
    }
}

// ---------------- log-softmax fallback (f32 logits in place) ----------------
__global__ __launch_bounds__(256) void lsm_k(float* __restrict__ lp) {
    const int r = blockIdx.x;
    const int tid = threadIdx.x;
    const int wid = tid >> 6, lane = tid & 63;
    __shared__ float wm[4], wl[4];
    float* row = lp + (size_t)r * V_;
    float mt = -1e30f, lt = 0.f;
    for (int i = tid * 4; i < V_; i += 1024) {
        float4 v = *(const float4*)&row[i];
        float c = fmaxf(fmaxf(v.x, v.y), fmaxf(v.z, v.w));
        if (c > mt) { lt *= __expf(mt - c); mt = c; }
        lt += __expf(v.x - mt) + __expf(v.y - mt) + __expf(v.z - mt) + __expf(v.w - mt);
    }
    #pragma unroll
    for (int off = 1; off <= 32; off <<= 1) {
        float m2 = __shfl_xor(mt, off), l2 = __shfl_xor(lt, off);
        float M = fmaxf(mt, m2);
        lt = lt * __expf(mt - M) + l2 * __expf(m2 - M);
        mt = M;
    }
    if (lane == 0) { wm[wid] = mt; wl[wid] = lt; }
    __syncthreads();
    float M4 = fmaxf(fmaxf(wm[0], wm[1]), fmaxf(wm[2], wm[3]));
    float L4 = wl[0] * __expf(wm[0] - M4) + wl[1] * __expf(wm[1] - M4)
             + wl[2] * __expf(wm[2] - M4) + wl[3] * __expf(wm[3] - M4);
    float sub = M4 + __logf(L4);
    for (int i = tid * 4; i < V_; i += 1024) {
        float4 v = *(const float4*)&row[i];
        v.x -= sub; v.y -= sub; v.z -= sub; v.w -= sub;
        *(float4*)&row[i] = v;
    }
}

// ---------------- log-softmax from bf16 logits, expanding in place to f32 ----------------
// Row r's bf16 logits occupy the FRONT HALF of row r's f32 slot range (ldcb = 2V).
// Descending-chunk in-place expansion; tail chunk predicated (V % 2048 != 0).
__global__ __launch_bounds__(256) void lsmx_k(float* __restrict__ lp) {
    const int r = blockIdx.x;
    const int tid = threadIdx.x;
    const int wid = tid >> 6, lane = tid & 63;
    __shared__ float wm[4], wl[4];
    float* row = lp + (size_t)r * V_;
    const __hip_bfloat16* brow = (const __hip_bfloat16*)row;

    float mt = -1e30f, lt = 0.f;
    for (int i = tid * 8; i < V_; i += 2048) {
        short8 v = *(const short8*)&brow[i];
        #pragma unroll
        for (int j = 0; j < 8; ++j) {
            float f = b2f((unsigned short)v[j]);
            if (f > mt) { lt *= __expf(mt - f); mt = f; }
            lt += __expf(f - mt);
        }
    }
    #pragma unroll
    for (int off = 1; off <= 32; off <<= 1) {
        float m2 = __shfl_xor(mt, off), l2 = __shfl_xor(lt, off);
        float M = fmaxf(mt, m2);
        lt = lt * __expf(mt - M) + l2 * __expf(m2 - M);
        mt = M;
    }
    if (lane == 0) { wm[wid] = mt; wl[wid] = lt; }
    __syncthreads();
    float M4 = fmaxf(fmaxf(wm[0], wm[1]), fmaxf(wm[2], wm[3]));
    float L4 = wl[0] * __expf(wm[0] - M4) + wl[1] * __expf(wm[1] - M4)
             + wl[2] * __expf(wm[2] - M4) + wl[3] * __expf(wm[3] - M4);
    float sub = M4 + __logf(L4);

    for (int ci = 15; ci >= 0; --ci) {
        const int c = ci * 2048 + tid * 8;
        const bool act = (c < V_);            // tail guard: V not a multiple of 2048
        short8 v;
        if (act) v = *(const short8*)&brow[c];
        __syncthreads();                      // all reads of this chunk done before writes
        if (act) {
            float4 o0, o1;
            o0.x = b2f((unsigned short)v[0]) - sub;
            o0.y = b2f((unsigned short)v[1]) - sub;
            o0.z = b2f((unsigned short)v[2]) - sub;
            o0.w = b2f((unsigned short)v[3]) - sub;
            o1.x = b2f((unsigned short)v[4]) - sub;
            o1.y = b2f((unsigned short)v[5]) - sub;
            o1.z = b2f((unsigned short)v[6]) - sub;
            o1.w = b2f((unsigned short)v[7]) - sub;
            *(float4*)&row[c] = o0;
            *(float4*)&row[c + 4] = o1;
        }
    }
}

extern "C" void kernel_launch(void* const* d_in, const int* in_sizes, int n_in,
                              void* d_out, int out_size, void* d_ws, size_t ws_size,
                              hipStream_t stream) {
    const int*   x    = (const int*)  d_in[0];
    const float* tok  = (const float*)d_in[1];
    const float* pos  = (const float*)d_in[2];
    const float* Wq   = (const float*)d_in[3];
    const float* bq   = (const float*)d_in[4];
    const float* Wk   = (const float*)d_in[5];
    const float* bk   = (const float*)d_in[6];
    const float* Wv   = (const float*)d_in[7];
    const float* bv   = (const float*)d_in[8];
    const float* Wo   = (const float*)d_in[9];
    const float* bo   = (const float*)d_in[10];
    const float* ln1g = (const float*)d_in[11];
    const float* ln1b = (const float*)d_in[12];
    const float* W1   = (const float*)d_in[13];
    const float* b1   = (const float*)d_in[14];
    const float* W2   = (const float*)d_in[15];
    const float* b2   = (const float*)d_in[16];
    const float* ln2g = (const float*)d_in[17];
    const float* ln2b = (const float*)d_in[18];
    const float* Wf   = (const float*)d_in[19];
    const float* bff  = (const float*)d_in[20];

    float* out = (float*)d_out;
    const size_t HS = (size_t)BS_ * D_;              // 1,572,864

    // f32-slot layout inside logits scratch region [0, BS_*V_):
    __hip_bfloat16* qkv_bf = (__hip_bfloat16*)out;               // BS*2304 bf16
    __hip_bfloat16* vT     = (__hip_bfloat16*)(out + 2359296);   // BS*768 bf16
    __hip_bfloat16* att_bf = (__hip_bfloat16*)(out + 4718592);
    float* tmp   = out + 5505024;
    float* h1    = out + 7077888;
    __hip_bfloat16* h1_bf  = (__hip_bfloat16*)(out + 8650752);
    __hip_bfloat16* ff_bf  = (__hip_bfloat16*)(out + 9437184);
    __hip_bfloat16* h_bf   = (__hip_bfloat16*)(out + 12582912);
    __hip_bfloat16* Wqkv_t = (__hip_bfloat16*)(out + 13369344);  // 6 x [2304][768]
    __hip_bfloat16* Wo_t   = (__hip_bfloat16*)(out + 18677760);  // 6 x [768][768]
    __hip_bfloat16* W1_t   = (__hip_bfloat16*)(out + 20447232);  // 6 x [3072][768]
    __hip_bfloat16* W2_t   = (__hip_bfloat16*)(out + 27525120);  // 6 x [768][3072]
    float* bqkv  = out + 34603008;                   // 6 x 2304
    float* h     = out + (size_t)BS_ * V_;           // tail: hset output

    const bool ws_ok = ws_size >= 52297728ULL;       // Wf_t (49.15MB) + hbf (3.15MB)
    __hip_bfloat16* Wf_t   = (__hip_bfloat16*)d_ws;              // [32000][768]
    __hip_bfloat16* hbf_ws = (__hip_bfloat16*)((char*)d_ws + 49152000);

    // ---- weight transpose/convert pre-pass ----
    const size_t DD = (size_t)D_ * D_, DF = (size_t)D_ * F_;
    const size_t QKVL = (size_t)NQKV_ * D_;
    transp_k<<<dim3(D_/32, D_/32, L_), 256, 0, stream>>>(Wq, DD, Wqkv_t,          QKVL, D_, D_);
    transp_k<<<dim3(D_/32, D_/32, L_), 256, 0, stream>>>(Wk, DD, Wqkv_t + DD,     QKVL, D_, D_);
    transp_k<<<dim3(D_/32, D_/32, L_), 256, 0, stream>>>(Wv, DD, Wqkv_t + 2 * DD, QKVL, D_, D_);
    transp_k<<<dim3(D_/32, D_/32, L_), 256, 0, stream>>>(Wo, DD, Wo_t,            DD,   D_, D_);
    transp_k<<<dim3(F_/32, D_/32, L_), 256, 0, stream>>>(W1, DF, W1_t,            DF,   F_, D_);
    transp_k<<<dim3(D_/32, F_/32, L_), 256, 0, stream>>>(W2, DF, W2_t,            DF,   D_, F_);
    bcat_k<<<L_, 256, 0, stream>>>(bq, bk, bv, bqkv);
    if (ws_ok)
        transp_k<<<dim3(V_/32, D_/32, 1), 256, 0, stream>>>(Wf, 0, Wf_t, 0, V_, D_);

    embed_k<<<BS_, 256, 0, stream>>>(x, tok, pos, h, h_bf);

    const dim3 gQKV(NQKV_/128, BS_/64);    // (18, 32) -> 576 blocks (BM=64)
    const dim3 gFF1(F_/128,    BS_/64);    // (24, 32) -> 768 blocks (BM=64)
    const dim3 gOUT64(D_/64,   BS_/64);    // (12, 32) -> 384 blocks
    const dim3 gA(S_/64, B_*H_);           // (16, 24)
    for (int i = 0; i < L_; ++i) {
        mgemm_k<64,128,0,false,true,false,false,true><<<gQKV, 256, 0, stream>>>(
            h_bf, Wqkv_t + (size_t)i * QKVL, bqkv + (size_t)i * NQKV_, nullptr, qkv_bf, vT, BS_, NQKV_, D_, NQKV_);
        fattn_k<<<gA, 256, 0, stream>>>(qkv_bf, vT, att_bf);
        mgemm_k<64,64,0,true,false,false,false,false><<<gOUT64, 256, 0, stream>>>(
            att_bf, Wo_t + (size_t)i * DD, bo + (size_t)i * D_, tmp, nullptr, nullptr, BS_, D_, D_, D_);
        addln_k<<<BS_, 256, 0, stream>>>(tmp, h, ln1g + (size_t)i * D_, ln1b + (size_t)i * D_, h1, h1_bf);
        mgemm_k<64,128,1,false,true,false,false,false><<<gFF1, 256, 0, stream>>>(
            h1_bf, W1_t + (size_t)i * DF, b1 + (size_t)i * F_, nullptr, ff_bf, nullptr, BS_, F_, D_, F_);
        mgemm_k<64,64,0,true,false,false,false,false><<<gOUT64, 256, 0, stream>>>(
            ff_bf, W2_t + (size_t)i * DF, b2 + (size_t)i * D_, tmp, nullptr, nullptr, BS_, D_, F_, D_);
        // last layer's bf16 hset goes straight to the logits-GEMM input buffer (skips cvt)
        __hip_bfloat16* obf = (i == L_ - 1 && ws_ok) ? hbf_ws : h_bf;
        addln_k<<<BS_, 256, 0, stream>>>(tmp, h1, ln2g + (size_t)i * D_, ln2b + (size_t)i * D_, h, obf);
    }

    if (ws_ok) {
        // bf16 logits parked at the front half of each output row (ldcb = 2V),
        // then lsmx expands in place to f32 log-probs.
        mgemm_k<128,128,0,false,true,true,true,false><<<dim3(BS_/128, V_/128), 256, 0, stream>>>(
            hbf_ws, Wf_t, bff, nullptr, (__hip_bfloat16*)out, nullptr, BS_, V_, D_, 2 * V_);
        lsmx_k<<<BS_, 256, 0, stream>>>(out);
    } else {
        gemm_k<<<dim3(V_/64, BS_/64), 256, 0, stream>>>(h, Wf, bff, out, BS_, V_, D_);
        lsm_k<<<BS_, 256, 0, stream>>>(out);
    }
}

// Round 16
// 1105.002 us; speedup vs baseline: 1.0216x; 1.0216x over previous
//
#include <hip/hip_runtime.h>
#include <hip/hip_bf16.h>
#include <math.h>

#define B_ 2
#define S_ 1024
#define V_ 32000
#define D_ 768
#define F_ 3072
#define H_ 12
#define L_ 6
#define DH_ 64
#define BS_ (B_*S_)   // 2048
#define NQKV_ 2304
#define KVB_ 128

typedef __attribute__((ext_vector_type(8))) short short8;
typedef __attribute__((ext_vector_type(4))) float f32x4;

__device__ __forceinline__ unsigned short f2b(float f) {
    union { __hip_bfloat16 h; unsigned short u; } cv;
    cv.h = __float2bfloat16(f);
    return cv.u;
}

__device__ __forceinline__ float b2f(unsigned short u) {
    union { unsigned int i; float f; } cv;
    cv.i = ((unsigned int)u) << 16;
    return cv.f;
}

__device__ __forceinline__ void store_bf4(__hip_bfloat16* p, float a, float b, float c, float d) {
    unsigned long long pk = (unsigned long long)f2b(a)
        | ((unsigned long long)f2b(b) << 16)
        | ((unsigned long long)f2b(c) << 32)
        | ((unsigned long long)f2b(d) << 48);
    *(unsigned long long*)p = pk;
}

__device__ __forceinline__ void gld16(const void* g, void* l) {
    __builtin_amdgcn_global_load_lds(
        (const __attribute__((address_space(1))) unsigned int*)g,
        (__attribute__((address_space(3))) unsigned int*)l,
        16, 0, 0);
}

// ---------------- embedding (dual write f32 + bf16) ----------------
__global__ void embed_k(const int* __restrict__ x, const float* __restrict__ tok,
                        const float* __restrict__ pos, float* __restrict__ h,
                        __hip_bfloat16* __restrict__ hbf) {
    int bs = blockIdx.x;
    int s = bs % S_;
    int t = x[bs];
    for (int d = threadIdx.x; d < D_; d += blockDim.x) {
        float v = tok[(size_t)t * D_ + d] + pos[(size_t)s * D_ + d];
        h[(size_t)bs * D_ + d] = v;
        hbf[(size_t)bs * D_ + d] = __float2bfloat16(v);
    }
}

// ---------------- transpose+convert: src f32 [K][N] -> dst bf16 [N][K] ----------------
__global__ __launch_bounds__(256) void transp_k(const float* __restrict__ src, size_t sl,
                                                __hip_bfloat16* __restrict__ dst, size_t dl,
                                                int N, int K) {
    const float* S = src + (size_t)blockIdx.z * sl;
    __hip_bfloat16* Dp = dst + (size_t)blockIdx.z * dl;
    __shared__ float T[32][33];
    const int k0 = blockIdx.y * 32, n0 = blockIdx.x * 32;
    const int tid = threadIdx.x;
    const int r = tid >> 3, c4 = (tid & 7) * 4;
    float4 vv = *(const float4*)&S[(size_t)(k0 + r) * N + n0 + c4];
    T[r][c4 + 0] = vv.x; T[r][c4 + 1] = vv.y; T[r][c4 + 2] = vv.z; T[r][c4 + 3] = vv.w;
    __syncthreads();
    store_bf4(&Dp[(size_t)(n0 + r) * K + k0 + c4],
              T[c4 + 0][r], T[c4 + 1][r], T[c4 + 2][r], T[c4 + 3][r]);
}

// ---------------- fused Wq/Wk/Wv transpose: z = layer*3 + which ----------------
// Q/K/V occupy consecutive 768-row blocks of Wqkv_t[2304][768] per layer.
__global__ __launch_bounds__(256) void qkvt_k(const float* __restrict__ Wq,
                                              const float* __restrict__ Wk,
                                              const float* __restrict__ Wv,
                                              __hip_bfloat16* __restrict__ Wqkv_t) {
    const int zi = blockIdx.z;
    const int layer = zi / 3, which = zi % 3;
    const size_t DD = (size_t)D_ * D_;
    const float* S = (which == 0 ? Wq : which == 1 ? Wk : Wv) + (size_t)layer * DD;
    __hip_bfloat16* Dp = Wqkv_t + (size_t)layer * ((size_t)NQKV_ * D_) + (size_t)which * DD;
    __shared__ float T[32][33];
    const int k0 = blockIdx.y * 32, n0 = blockIdx.x * 32;
    const int tid = threadIdx.x;
    const int r = tid >> 3, c4 = (tid & 7) * 4;
    float4 vv = *(const float4*)&S[(size_t)(k0 + r) * D_ + n0 + c4];
    T[r][c4 + 0] = vv.x; T[r][c4 + 1] = vv.y; T[r][c4 + 2] = vv.z; T[r][c4 + 3] = vv.w;
    __syncthreads();
    store_bf4(&Dp[(size_t)(n0 + r) * D_ + k0 + c4],
              T[c4 + 0][r], T[c4 + 1][r], T[c4 + 2][r], T[c4 + 3][r]);
}

// ---------------- concat qkv biases ----------------
__global__ void bcat_k(const float* __restrict__ bq, const float* __restrict__ bk,
                       const float* __restrict__ bv, float* __restrict__ dst) {
    int l = blockIdx.x;
    for (int j = threadIdx.x; j < D_; j += blockDim.x) {
        dst[(size_t)l * NQKV_ + j]          = bq[(size_t)l * D_ + j];
        dst[(size_t)l * NQKV_ + D_ + j]     = bk[(size_t)l * D_ + j];
        dst[(size_t)l * NQKV_ + 2 * D_ + j] = bv[(size_t)l * D_ + j];
    }
}

// ---------------- MFMA bf16 GEMM: C = act(A[M,K] @ Bt[N,K]^T + bias) ----------------
// LDS tiles XOR-swizzled (T2). SW: M on blockIdx.x. XS: XCD-bijective swizzle.
// WVT: QKV mode -- V-cols -> vT[bh][d][s], Q-cols pre-scaled. ldcb = bf16 C row stride.
template<int BM, int BN, int ACT, bool WF32, bool WBF, bool SW, bool XS, bool WVT>
__global__ __launch_bounds__(256) void mgemm_k(const __hip_bfloat16* __restrict__ A,
                                               const __hip_bfloat16* __restrict__ Bt,
                                               const float* __restrict__ bias,
                                               float* __restrict__ Cf,
                                               __hip_bfloat16* __restrict__ Cb,
                                               __hip_bfloat16* __restrict__ vTp,
                                               int M, int N, int K, int ldcb) {
    constexpr int WM = BM / 2, WN = BN / 2;
    constexpr int FM = WM / 16, FN = WN / 16;
    __shared__ __hip_bfloat16 Al[BM * 64];
    __shared__ __hip_bfloat16 Bl[BN * 64];
    const int tid = threadIdx.x;
    const int wid = tid >> 6, lane = tid & 63;
    const int wr = wid >> 1, wc = wid & 1;
    const int lrow = lane & 15, kq = lane >> 4;

    int bx = blockIdx.x, by = blockIdx.y;
    if (XS) {
        const int gx = gridDim.x;
        const int nwg = gx * gridDim.y;
        const int lin = by * gx + bx;
        const int logical = (lin & 7) * (nwg >> 3) + (lin >> 3);
        bx = logical % gx;
        by = logical / gx;
    }
    const int row0 = (SW ? bx : by) * BM;
    const int col0 = (SW ? by : bx) * BN;

    f32x4 acc[FM][FN];
    #pragma unroll
    for (int i = 0; i < FM; ++i)
        #pragma unroll
        for (int j = 0; j < FN; ++j)
            acc[i][j] = (f32x4){0.f, 0.f, 0.f, 0.f};

    const int srow = (lane >> 3);
    const int scol = ((lane & 7) ^ srow) * 8;   // pre-swizzled source chunk (T21)

    for (int kk = 0; kk < K; kk += 64) {
        #pragma unroll
        for (int i = 0; i < BM / 32; ++i)
            gld16(A + (size_t)(row0 + i * 32 + wid * 8 + srow) * K + kk + scol,
                  &Al[(i * 32 + wid * 8) * 64]);
        #pragma unroll
        for (int i = 0; i < BN / 32; ++i)
            gld16(Bt + (size_t)(col0 + i * 32 + wid * 8 + srow) * K + kk + scol,
                  &Bl[(i * 32 + wid * 8) * 64]);
        __syncthreads();

        #pragma unroll
        for (int kc = 0; kc < 2; ++kc) {
            short8 af[FM], bfr[FN];
            #pragma unroll
            for (int i = 0; i < FM; ++i) {
                const int row = wr * WM + i * 16 + lrow;
                af[i] = *(const short8*)((const char*)Al + row * 128
                          + ((kc * 64 + kq * 16) ^ ((row & 7) << 4)));
            }
            #pragma unroll
            for (int j = 0; j < FN; ++j) {
                const int row = wc * WN + j * 16 + lrow;
                bfr[j] = *(const short8*)((const char*)Bl + row * 128
                          + ((kc * 64 + kq * 16) ^ ((row & 7) << 4)));
            }
            #pragma unroll
            for (int i = 0; i < FM; ++i)
                #pragma unroll
                for (int j = 0; j < FN; ++j)
                    acc[i][j] = __builtin_amdgcn_mfma_f32_16x16x32_bf16(af[i], bfr[j], acc[i][j], 0, 0, 0);
        }
        __syncthreads();
    }

    #pragma unroll
    for (int i = 0; i < FM; ++i)
        #pragma unroll
        for (int j = 0; j < FN; ++j) {
            const int col = col0 + wc * WN + j * 16 + lrow;
            const float bv = bias[col];
            const int rowq = row0 + wr * WM + i * 16 + kq * 4;
            if (WVT && col >= 1536) {
                const int cv = col - 1536;
                const int bh = (rowq >> 10) * H_ + (cv >> 6);
                store_bf4(&vTp[((size_t)bh * DH_ + (cv & 63)) * S_ + (rowq & 1023)],
                          acc[i][j][0] + bv, acc[i][j][1] + bv,
                          acc[i][j][2] + bv, acc[i][j][3] + bv);
            } else {
                #pragma unroll
                for (int r = 0; r < 4; ++r) {
                    const int row = rowq + r;
                    float vv = acc[i][j][r] + bv;
                    if (ACT == 1) vv = 0.5f * vv * (1.0f + erff(vv * 0.70710678118654752f));
                    if (WVT && col < D_) vv *= 0.03608439182435161f;  // fold attn scale into Q
                    if (WF32) Cf[(size_t)row * N + col] = vv;
                    if (WBF)  Cb[(size_t)row * ldcb + col] = __float2bfloat16(vv);
                }
            }
        }
}

// ---------------- legacy f32 GEMM (fallback for logits if no workspace) ----------------
__global__ __launch_bounds__(256) void gemm_k(const float* __restrict__ A,
                                              const float* __restrict__ W,
                                              const float* __restrict__ bias,
                                              float* __restrict__ Cout,
                                              int M, int N, int K) {
    __shared__ float As[64][16];
    __shared__ float Bs[16][64];
    const int tid = threadIdx.x;
    const int tx = tid & 15, ty = tid >> 4;
    const int row0 = blockIdx.y * 64, col0 = blockIdx.x * 64;
    float acc[4][4] = {};

    for (int kk = 0; kk < K; kk += 16) {
        #pragma unroll
        for (int it = 0; it < 4; ++it) {
            int idx = tid + it * 256;
            int m = idx >> 4, k = idx & 15;
            As[m][k] = A[(size_t)(row0 + m) * K + kk + k];
            int r = idx >> 6, c = idx & 63;
            Bs[r][c] = W[(size_t)(kk + r) * N + col0 + c];
        }
        __syncthreads();
        #pragma unroll
        for (int k = 0; k < 16; ++k) {
            float a[4], b[4];
            #pragma unroll
            for (int i = 0; i < 4; ++i) a[i] = As[ty * 4 + i][k];
            #pragma unroll
            for (int j = 0; j < 4; ++j) b[j] = Bs[k][tx * 4 + j];
            #pragma unroll
            for (int i = 0; i < 4; ++i)
                #pragma unroll
                for (int j = 0; j < 4; ++j)
                    acc[i][j] += a[i] * b[j];
        }
        __syncthreads();
    }

    #pragma unroll
    for (int i = 0; i < 4; ++i) {
        int r = row0 + ty * 4 + i;
        #pragma unroll
        for (int j = 0; j < 4; ++j) {
            int c = col0 + tx * 4 + j;
            Cout[(size_t)r * N + c] = acc[i][j] + bias[c];
        }
    }
}

// ---------------- MFMA flash attention, double-buffered KV + defer-rescale (T3+T13) ----------------
// KVB=128 (measured-best; KVB=64 occupancy experiment regressed, r14).
__global__ __launch_bounds__(256) void fattn_k(const __hip_bfloat16* __restrict__ qkv,
                                               const __hip_bfloat16* __restrict__ vT,
                                               __hip_bfloat16* __restrict__ o) {
    const int qt0 = blockIdx.x * 64;
    const int bh = blockIdx.y;
    const int b = bh / H_, hh = bh % H_;
    const size_t rb = (size_t)b * S_;
    const int hoff = hh * DH_;

    __shared__ __hip_bfloat16 Ks[2][KVB_ * 64];   // 2 x 16 KB
    __shared__ __hip_bfloat16 Vt[2][64 * KVB_];   // 2 x 16 KB
    __shared__ __hip_bfloat16 Ps[64 * KVB_];      // 16 KB

    const int tid = threadIdx.x;
    const int w = tid >> 6, lane = tid & 63;
    const int lr = lane & 15, lk = lane >> 4;
    const size_t vbase = (size_t)bh * DH_ * S_;

    short8 aq[2];
    {
        const int qrow = qt0 + w * 16 + lr;
        #pragma unroll
        for (int kc = 0; kc < 2; ++kc)
            aq[kc] = *(const short8*)&qkv[(rb + qrow) * NQKV_ + hoff + kc * 32 + lk * 8];
    }

    f32x4 oacc[4];
    float m_i[4], l_i[4];
    #pragma unroll
    for (int r = 0; r < 4; ++r) {
        oacc[r] = (f32x4){0.f, 0.f, 0.f, 0.f};
        m_i[r] = -1e30f;
        l_i[r] = 0.f;
    }

    auto stage = [&](int bi, int kt0) {
        #pragma unroll
        for (int t = 0; t < 4; ++t) {
            const int r0 = w * 32 + t * 8;
            const int r = r0 + (lane >> 3);
            const int cs = (lane & 7) ^ ((r & 7) ^ ((r >> 3) & 7));
            gld16(&qkv[(rb + kt0 + r) * NQKV_ + D_ + hoff + cs * 8], &Ks[bi][r0 * 64]);
        }
        #pragma unroll
        for (int t = 0; t < 4; ++t) {
            const int d0 = w * 16 + t * 4;
            const int d = d0 + (lane >> 4);
            const int cs = (lane & 15) ^ (d & 15);
            gld16(&vT[vbase + (size_t)d * S_ + kt0 + cs * 8], &Vt[bi][d0 * 128]);
        }
    };

    stage(0, 0);                                   // prologue
    int cur = 0;
    for (int kt0 = 0; kt0 < S_; kt0 += KVB_) {
        __syncthreads();                           // buf[cur] loads drained; prev compute done
        if (kt0 + KVB_ < S_) stage(cur ^ 1, kt0 + KVB_);   // overlap next-tile loads w/ compute
        const char* Kb = (const char*)Ks[cur];
        const char* Vb = (const char*)Vt[cur];

        // ---- scores S = Q @ K^T (Q pre-scaled in QKV epilogue) ----
        f32x4 s[8];
        #pragma unroll
        for (int j = 0; j < 8; ++j) s[j] = (f32x4){0.f, 0.f, 0.f, 0.f};
        __builtin_amdgcn_s_setprio(1);
        #pragma unroll
        for (int kc = 0; kc < 2; ++kc) {
            #pragma unroll
            for (int j = 0; j < 8; ++j) {
                int kr = j * 16 + lr;
                short8 bk = *(const short8*)(Kb + kr * 128
                              + ((kc * 64 + lk * 16) ^ ((((kr & 7) ^ ((kr >> 3) & 7)) << 4))));
                s[j] = __builtin_amdgcn_mfma_f32_16x16x32_bf16(aq[kc], bk, s[j], 0, 0, 0);
            }
        }
        __builtin_amdgcn_s_setprio(0);

        // ---- online softmax with defer-rescale (T13, THR=8) ----
        float tmax[4];
        #pragma unroll
        for (int r = 0; r < 4; ++r) {
            float t = s[0][r];
            #pragma unroll
            for (int j = 1; j < 8; ++j) t = fmaxf(t, s[j][r]);
            tmax[r] = t;
        }
        float excess = fmaxf(fmaxf(tmax[0] - m_i[0], tmax[1] - m_i[1]),
                             fmaxf(tmax[2] - m_i[2], tmax[3] - m_i[3]));
        if (!__all(excess <= 8.0f)) {
            #pragma unroll
            for (int r = 0; r < 4; ++r) {
                float tm = tmax[r];
                #pragma unroll
                for (int off = 1; off <= 8; off <<= 1)
                    tm = fmaxf(tm, __shfl_xor(tm, off));
                float mnew = fmaxf(m_i[r], tm);
                float corr = __expf(m_i[r] - mnew);
                m_i[r] = mnew;
                l_i[r] *= corr;
                #pragma unroll
                for (int jd = 0; jd < 4; ++jd) oacc[jd][r] *= corr;
            }
        }
        #pragma unroll
        for (int r = 0; r < 4; ++r) {
            float psum = 0.f;
            const int prow = w * 16 + lk * 4 + r;
            #pragma unroll
            for (int j = 0; j < 8; ++j) {
                float p = __expf(s[j][r] - m_i[r]);     // bounded by e^8
                psum += p;
                *(__hip_bfloat16*)((char*)Ps + prow * 256
                    + (((j * 16 + lr) * 2) ^ ((prow & 15) << 4))) = __float2bfloat16(p);
            }
            #pragma unroll
            for (int off = 1; off <= 8; off <<= 1)
                psum += __shfl_xor(psum, off);
            l_i[r] += psum;
        }

        // ---- PV: O += P @ V (Ps rows wave-private) ----
        __builtin_amdgcn_s_setprio(1);
        #pragma unroll
        for (int ks = 0; ks < 4; ++ks) {
            const int prow = w * 16 + lr;
            short8 pa = *(const short8*)((const char*)Ps + prow * 256
                          + ((ks * 64 + lk * 16) ^ ((prow & 15) << 4)));
            #pragma unroll
            for (int jd = 0; jd < 4; ++jd) {
                int vr = jd * 16 + lr;
                short8 vb = *(const short8*)(Vb + vr * 256
                              + ((ks * 64 + lk * 16) ^ ((vr & 15) << 4)));
                oacc[jd] = __builtin_amdgcn_mfma_f32_16x16x32_bf16(pa, vb, oacc[jd], 0, 0, 0);
            }
        }
        __builtin_amdgcn_s_setprio(0);
        cur ^= 1;
    }

    #pragma unroll
    for (int r = 0; r < 4; ++r) {
        float inv = 1.0f / l_i[r];
        const int row = qt0 + w * 16 + lk * 4 + r;
        #pragma unroll
        for (int jd = 0; jd < 4; ++jd)
            o[(rb + row) * (size_t)D_ + hoff + jd * 16 + lr] = __float2bfloat16(oacc[jd][r] * inv);
    }
}

// ---------------- add + layernorm; single-pass wave-reduce (1 barrier) ----------------
__global__ __launch_bounds__(256) void addln_k(const float* __restrict__ a,
                                               const float* __restrict__ b,
                                               const float* __restrict__ g,
                                               const float* __restrict__ beta,
                                               float* __restrict__ out,
                                               __hip_bfloat16* __restrict__ out_bf) {
    const int r = blockIdx.x;
    const int tid = threadIdx.x;
    const int wid = tid >> 6, lane = tid & 63;
    __shared__ float w1[4], w2[4];
    float xv[3];
    float s1 = 0.f, s2 = 0.f;
    #pragma unroll
    for (int i = 0; i < 3; ++i) {
        int d = tid + i * 256;
        xv[i] = a[(size_t)r * D_ + d] + b[(size_t)r * D_ + d];
        s1 += xv[i];
        s2 += xv[i] * xv[i];
    }
    #pragma unroll
    for (int off = 1; off <= 32; off <<= 1) {
        s1 += __shfl_xor(s1, off);
        s2 += __shfl_xor(s2, off);
    }
    if (lane == 0) { w1[wid] = s1; w2[wid] = s2; }
    __syncthreads();
    s1 = w1[0] + w1[1] + w1[2] + w1[3];
    s2 = w2[0] + w2[1] + w2[2] + w2[3];
    float mu = s1 * (1.0f / D_);
    float var = s2 * (1.0f / D_) - mu * mu;
    float rstd = rsqrtf(var + 1e-5f);
    #pragma unroll
    for (int i = 0; i < 3; ++i) {
        int d = tid + i * 256;
        float v = (xv[i] - mu) * rstd * g[d] + beta[d];
        out[(size_t)r * D_ + d] = v;
        out_bf[(size_t)r * D_ + d] = __float2bfloat16(v);
    }
}

// ---------------- log-softmax fallback (f32 logits in place) ----------------
__global__ __launch_bounds__(256) void lsm_k(float* __restrict__ lp) {
    const int r = blockIdx.x;
    const int tid = threadIdx.x;
    const int wid = tid >> 6, lane = tid & 63;
    __shared__ float wm[4], wl[4];
    float* row = lp + (size_t)r * V_;
    float mt = -1e30f, lt = 0.f;
    for (int i = tid * 4; i < V_; i += 1024) {
        float4 v = *(const float4*)&row[i];
        float c = fmaxf(fmaxf(v.x, v.y), fmaxf(v.z, v.w));
        if (c > mt) { lt *= __expf(mt - c); mt = c; }
        lt += __expf(v.x - mt) + __expf(v.y - mt) + __expf(v.z - mt) + __expf(v.w - mt);
    }
    #pragma unroll
    for (int off = 1; off <= 32; off <<= 1) {
        float m2 = __shfl_xor(mt, off), l2 = __shfl_xor(lt, off);
        float M = fmaxf(mt, m2);
        lt = lt * __expf(mt - M) + l2 * __expf(m2 - M);
        mt = M;
    }
    if (lane == 0) { wm[wid] = mt; wl[wid] = lt; }
    __syncthreads();
    float M4 = fmaxf(fmaxf(wm[0], wm[1]), fmaxf(wm[2], wm[3]));
    float L4 = wl[0] * __expf(wm[0] - M4) + wl[1] * __expf(wm[1] - M4)
             + wl[2] * __expf(wm[2] - M4) + wl[3] * __expf(wm[3] - M4);
    float sub = M4 + __logf(L4);
    for (int i = tid * 4; i < V_; i += 1024) {
        float4 v = *(const float4*)&row[i];
        v.x -= sub; v.y -= sub; v.z -= sub; v.w -= sub;
        *(float4*)&row[i] = v;
    }
}

// ---------------- log-softmax from bf16 logits, expanding in place to f32 ----------------
// Row r's bf16 logits occupy the FRONT HALF of row r's f32 slot range (ldcb = 2V).
// Descending-chunk in-place expansion; tail chunk predicated (V % 2048 != 0).
__global__ __launch_bounds__(256) void lsmx_k(float* __restrict__ lp) {
    const int r = blockIdx.x;
    const int tid = threadIdx.x;
    const int wid = tid >> 6, lane = tid & 63;
    __shared__ float wm[4], wl[4];
    float* row = lp + (size_t)r * V_;
    const __hip_bfloat16* brow = (const __hip_bfloat16*)row;

    float mt = -1e30f, lt = 0.f;
    for (int i = tid * 8; i < V_; i += 2048) {
        short8 v = *(const short8*)&brow[i];
        #pragma unroll
        for (int j = 0; j < 8; ++j) {
            float f = b2f((unsigned short)v[j]);
            if (f > mt) { lt *= __expf(mt - f); mt = f; }
            lt += __expf(f - mt);
        }
    }
    #pragma unroll
    for (int off = 1; off <= 32; off <<= 1) {
        float m2 = __shfl_xor(mt, off), l2 = __shfl_xor(lt, off);
        float M = fmaxf(mt, m2);
        lt = lt * __expf(mt - M) + l2 * __expf(m2 - M);
        mt = M;
    }
    if (lane == 0) { wm[wid] = mt; wl[wid] = lt; }
    __syncthreads();
    float M4 = fmaxf(fmaxf(wm[0], wm[1]), fmaxf(wm[2], wm[3]));
    float L4 = wl[0] * __expf(wm[0] - M4) + wl[1] * __expf(wm[1] - M4)
             + wl[2] * __expf(wm[2] - M4) + wl[3] * __expf(wm[3] - M4);
    float sub = M4 + __logf(L4);

    for (int ci = 15; ci >= 0; --ci) {
        const int c = ci * 2048 + tid * 8;
        const bool act = (c < V_);            // tail guard: V not a multiple of 2048
        short8 v;
        if (act) v = *(const short8*)&brow[c];
        __syncthreads();                      // all reads of this chunk done before writes
        if (act) {
            float4 o0, o1;
            o0.x = b2f((unsigned short)v[0]) - sub;
            o0.y = b2f((unsigned short)v[1]) - sub;
            o0.z = b2f((unsigned short)v[2]) - sub;
            o0.w = b2f((unsigned short)v[3]) - sub;
            o1.x = b2f((unsigned short)v[4]) - sub;
            o1.y = b2f((unsigned short)v[5]) - sub;
            o1.z = b2f((unsigned short)v[6]) - sub;
            o1.w = b2f((unsigned short)v[7]) - sub;
            *(float4*)&row[c] = o0;
            *(float4*)&row[c + 4] = o1;
        }
    }
}

extern "C" void kernel_launch(void* const* d_in, const int* in_sizes, int n_in,
                              void* d_out, int out_size, void* d_ws, size_t ws_size,
                              hipStream_t stream) {
    const int*   x    = (const int*)  d_in[0];
    const float* tok  = (const float*)d_in[1];
    const float* pos  = (const float*)d_in[2];
    const float* Wq   = (const float*)d_in[3];
    const float* bq   = (const float*)d_in[4];
    const float* Wk   = (const float*)d_in[5];
    const float* bk   = (const float*)d_in[6];
    const float* Wv   = (const float*)d_in[7];
    const float* bv   = (const float*)d_in[8];
    const float* Wo   = (const float*)d_in[9];
    const float* bo   = (const float*)d_in[10];
    const float* ln1g = (const float*)d_in[11];
    const float* ln1b = (const float*)d_in[12];
    const float* W1   = (const float*)d_in[13];
    const float* b1   = (const float*)d_in[14];
    const float* W2   = (const float*)d_in[15];
    const float* b2   = (const float*)d_in[16];
    const float* ln2g = (const float*)d_in[17];
    const float* ln2b = (const float*)d_in[18];
    const float* Wf   = (const float*)d_in[19];
    const float* bff  = (const float*)d_in[20];

    float* out = (float*)d_out;
    const size_t HS = (size_t)BS_ * D_;              // 1,572,864

    // f32-slot layout inside logits scratch region [0, BS_*V_):
    __hip_bfloat16* qkv_bf = (__hip_bfloat16*)out;               // BS*2304 bf16
    __hip_bfloat16* vT     = (__hip_bfloat16*)(out + 2359296);   // BS*768 bf16
    __hip_bfloat16* att_bf = (__hip_bfloat16*)(out + 4718592);
    float* tmp   = out + 5505024;
    float* h1    = out + 7077888;
    __hip_bfloat16* h1_bf  = (__hip_bfloat16*)(out + 8650752);
    __hip_bfloat16* ff_bf  = (__hip_bfloat16*)(out + 9437184);
    __hip_bfloat16* h_bf   = (__hip_bfloat16*)(out + 12582912);
    __hip_bfloat16* Wqkv_t = (__hip_bfloat16*)(out + 13369344);  // 6 x [2304][768]
    __hip_bfloat16* Wo_t   = (__hip_bfloat16*)(out + 18677760);  // 6 x [768][768]
    __hip_bfloat16* W1_t   = (__hip_bfloat16*)(out + 20447232);  // 6 x [3072][768]
    __hip_bfloat16* W2_t   = (__hip_bfloat16*)(out + 27525120);  // 6 x [768][3072]
    float* bqkv  = out + 34603008;                   // 6 x 2304
    float* h     = out + (size_t)BS_ * V_;           // tail: hset output

    const bool ws_ok = ws_size >= 52297728ULL;       // Wf_t (49.15MB) + hbf (3.15MB)
    __hip_bfloat16* Wf_t   = (__hip_bfloat16*)d_ws;              // [32000][768]
    __hip_bfloat16* hbf_ws = (__hip_bfloat16*)((char*)d_ws + 49152000);

    // ---- weight transpose/convert pre-pass ----
    const size_t DD = (size_t)D_ * D_, DF = (size_t)D_ * F_;
    const size_t QKVL = (size_t)NQKV_ * D_;
    qkvt_k<<<dim3(D_/32, D_/32, 3 * L_), 256, 0, stream>>>(Wq, Wk, Wv, Wqkv_t);
    transp_k<<<dim3(D_/32, D_/32, L_), 256, 0, stream>>>(Wo, DD, Wo_t, DD,   D_, D_);
    transp_k<<<dim3(F_/32, D_/32, L_), 256, 0, stream>>>(W1, DF, W1_t, DF,   F_, D_);
    transp_k<<<dim3(D_/32, F_/32, L_), 256, 0, stream>>>(W2, DF, W2_t, DF,   D_, F_);
    bcat_k<<<L_, 256, 0, stream>>>(bq, bk, bv, bqkv);
    if (ws_ok)
        transp_k<<<dim3(V_/32, D_/32, 1), 256, 0, stream>>>(Wf, 0, Wf_t, 0, V_, D_);

    embed_k<<<BS_, 256, 0, stream>>>(x, tok, pos, h, h_bf);

    const dim3 gQKV(NQKV_/128, BS_/64);    // (18, 32) -> 576 blocks (BM=64)
    const dim3 gFF1(F_/128,    BS_/64);    // (24, 32) -> 768 blocks (BM=64)
    const dim3 gOUT64(D_/64,   BS_/64);    // (12, 32) -> 384 blocks
    const dim3 gA(S_/64, B_*H_);           // (16, 24)
    for (int i = 0; i < L_; ++i) {
        mgemm_k<64,128,0,false,true,false,false,true><<<gQKV, 256, 0, stream>>>(
            h_bf, Wqkv_t + (size_t)i * QKVL, bqkv + (size_t)i * NQKV_, nullptr, qkv_bf, vT, BS_, NQKV_, D_, NQKV_);
        fattn_k<<<gA, 256, 0, stream>>>(qkv_bf, vT, att_bf);
        mgemm_k<64,64,0,true,false,false,false,false><<<gOUT64, 256, 0, stream>>>(
            att_bf, Wo_t + (size_t)i * DD, bo + (size_t)i * D_, tmp, nullptr, nullptr, BS_, D_, D_, D_);
        addln_k<<<BS_, 256, 0, stream>>>(tmp, h, ln1g + (size_t)i * D_, ln1b + (size_t)i * D_, h1, h1_bf);
        mgemm_k<64,128,1,false,true,false,false,false><<<gFF1, 256, 0, stream>>>(
            h1_bf, W1_t + (size_t)i * DF, b1 + (size_t)i * F_, nullptr, ff_bf, nullptr, BS_, F_, D_, F_);
        mgemm_k<64,64,0,true,false,false,false,false><<<gOUT64, 256, 0, stream>>>(
            ff_bf, W2_t + (size_t)i * DF, b2 + (size_t)i * D_, tmp, nullptr, nullptr, BS_, D_, F_, D_);
        // last layer's bf16 hset goes straight to the logits-GEMM input buffer (skips cvt)
        __hip_bfloat16* obf = (i == L_ - 1 && ws_ok) ? hbf_ws : h_bf;
        addln_k<<<BS_, 256, 0, stream>>>(tmp, h1, ln2g + (size_t)i * D_, ln2b + (size_t)i * D_, h, obf);
    }

    if (ws_ok) {
        // bf16 logits parked at the front half of each output row (ldcb = 2V),
        // then lsmx expands in place to f32 log-probs.
        mgemm_k<128,128,0,false,true,true,true,false><<<dim3(BS_/128, V_/128), 256, 0, stream>>>(
            hbf_ws, Wf_t, bff, nullptr, (__hip_bfloat16*)out, nullptr, BS_, V_, D_, 2 * V_);
        lsmx_k<<<BS_, 256, 0, stream>>>(out);
    } else {
        gemm_k<<<dim3(V_/64, BS_/64), 256, 0, stream>>>(h, Wf, bff, out, BS_, V_, D_);
        lsm_k<<<BS_, 256, 0, stream>>>(out);
    }
}

// Round 17
// 1098.736 us; speedup vs baseline: 1.0274x; 1.0057x over previous
//
#include <hip/hip_runtime.h>
#include <hip/hip_bf16.h>
#include <math.h>

#define B_ 2
#define S_ 1024
#define V_ 32000
#define D_ 768
#define F_ 3072
#define H_ 12
#define L_ 6
#define DH_ 64
#define BS_ (B_*S_)   // 2048
#define NQKV_ 2304
#define KVB_ 128

typedef __attribute__((ext_vector_type(8))) short short8;
typedef __attribute__((ext_vector_type(4))) float f32x4;

__device__ __forceinline__ unsigned short f2b(float f) {
    union { __hip_bfloat16 h; unsigned short u; } cv;
    cv.h = __float2bfloat16(f);
    return cv.u;
}

__device__ __forceinline__ float b2f(unsigned short u) {
    union { unsigned int i; float f; } cv;
    cv.i = ((unsigned int)u) << 16;
    return cv.f;
}

__device__ __forceinline__ void store_bf4(__hip_bfloat16* p, float a, float b, float c, float d) {
    unsigned long long pk = (unsigned long long)f2b(a)
        | ((unsigned long long)f2b(b) << 16)
        | ((unsigned long long)f2b(c) << 32)
        | ((unsigned long long)f2b(d) << 48);
    *(unsigned long long*)p = pk;
}

__device__ __forceinline__ void gld16(const void* g, void* l) {
    __builtin_amdgcn_global_load_lds(
        (const __attribute__((address_space(1))) unsigned int*)g,
        (__attribute__((address_space(3))) unsigned int*)l,
        16, 0, 0);
}

// ---------------- embedding (dual write f32 + bf16) ----------------
__global__ void embed_k(const int* __restrict__ x, const float* __restrict__ tok,
                        const float* __restrict__ pos, float* __restrict__ h,
                        __hip_bfloat16* __restrict__ hbf) {
    int bs = blockIdx.x;
    int s = bs % S_;
    int t = x[bs];
    for (int d = threadIdx.x; d < D_; d += blockDim.x) {
        float v = tok[(size_t)t * D_ + d] + pos[(size_t)s * D_ + d];
        h[(size_t)bs * D_ + d] = v;
        hbf[(size_t)bs * D_ + d] = __float2bfloat16(v);
    }
}

// ---------------- transpose+convert: src f32 [K][N] -> dst bf16 [N][K] ----------------
__global__ __launch_bounds__(256) void transp_k(const float* __restrict__ src, size_t sl,
                                                __hip_bfloat16* __restrict__ dst, size_t dl,
                                                int N, int K) {
    const float* S = src + (size_t)blockIdx.z * sl;
    __hip_bfloat16* Dp = dst + (size_t)blockIdx.z * dl;
    __shared__ float T[32][33];
    const int k0 = blockIdx.y * 32, n0 = blockIdx.x * 32;
    const int tid = threadIdx.x;
    const int r = tid >> 3, c4 = (tid & 7) * 4;
    float4 vv = *(const float4*)&S[(size_t)(k0 + r) * N + n0 + c4];
    T[r][c4 + 0] = vv.x; T[r][c4 + 1] = vv.y; T[r][c4 + 2] = vv.z; T[r][c4 + 3] = vv.w;
    __syncthreads();
    store_bf4(&Dp[(size_t)(n0 + r) * K + k0 + c4],
              T[c4 + 0][r], T[c4 + 1][r], T[c4 + 2][r], T[c4 + 3][r]);
}

// ---------------- fused Wq/Wk/Wv transpose: z = layer*3 + which ----------------
__global__ __launch_bounds__(256) void qkvt_k(const float* __restrict__ Wq,
                                              const float* __restrict__ Wk,
                                              const float* __restrict__ Wv,
                                              __hip_bfloat16* __restrict__ Wqkv_t) {
    const int zi = blockIdx.z;
    const int layer = zi / 3, which = zi % 3;
    const size_t DD = (size_t)D_ * D_;
    const float* S = (which == 0 ? Wq : which == 1 ? Wk : Wv) + (size_t)layer * DD;
    __hip_bfloat16* Dp = Wqkv_t + (size_t)layer * ((size_t)NQKV_ * D_) + (size_t)which * DD;
    __shared__ float T[32][33];
    const int k0 = blockIdx.y * 32, n0 = blockIdx.x * 32;
    const int tid = threadIdx.x;
    const int r = tid >> 3, c4 = (tid & 7) * 4;
    float4 vv = *(const float4*)&S[(size_t)(k0 + r) * D_ + n0 + c4];
    T[r][c4 + 0] = vv.x; T[r][c4 + 1] = vv.y; T[r][c4 + 2] = vv.z; T[r][c4 + 3] = vv.w;
    __syncthreads();
    store_bf4(&Dp[(size_t)(n0 + r) * D_ + k0 + c4],
              T[c4 + 0][r], T[c4 + 1][r], T[c4 + 2][r], T[c4 + 3][r]);
}

// ---------------- concat qkv biases ----------------
__global__ void bcat_k(const float* __restrict__ bq, const float* __restrict__ bk,
                       const float* __restrict__ bv, float* __restrict__ dst) {
    int l = blockIdx.x;
    for (int j = threadIdx.x; j < D_; j += blockDim.x) {
        dst[(size_t)l * NQKV_ + j]          = bq[(size_t)l * D_ + j];
        dst[(size_t)l * NQKV_ + D_ + j]     = bk[(size_t)l * D_ + j];
        dst[(size_t)l * NQKV_ + 2 * D_ + j] = bv[(size_t)l * D_ + j];
    }
}

// ---------------- MFMA bf16 GEMM: C = act(A[M,K] @ Bt[N,K]^T + bias) ----------------
// LDS tiles XOR-swizzled (T2). SW: M on blockIdx.x. XS: XCD-bijective swizzle.
// WVT: QKV mode -- V-cols -> vT[bh][d][s], Q-cols pre-scaled. ldcb = bf16 C row
// stride. NT: non-temporal bf16 C stores (logits stream -- never re-read from L2;
// avoids evicting the Wf panel this XCD is working from).
template<int BM, int BN, int ACT, bool WF32, bool WBF, bool SW, bool XS, bool WVT, bool NT>
__global__ __launch_bounds__(256) void mgemm_k(const __hip_bfloat16* __restrict__ A,
                                               const __hip_bfloat16* __restrict__ Bt,
                                               const float* __restrict__ bias,
                                               float* __restrict__ Cf,
                                               __hip_bfloat16* __restrict__ Cb,
                                               __hip_bfloat16* __restrict__ vTp,
                                               int M, int N, int K, int ldcb) {
    constexpr int WM = BM / 2, WN = BN / 2;
    constexpr int FM = WM / 16, FN = WN / 16;
    __shared__ __hip_bfloat16 Al[BM * 64];
    __shared__ __hip_bfloat16 Bl[BN * 64];
    const int tid = threadIdx.x;
    const int wid = tid >> 6, lane = tid & 63;
    const int wr = wid >> 1, wc = wid & 1;
    const int lrow = lane & 15, kq = lane >> 4;

    int bx = blockIdx.x, by = blockIdx.y;
    if (XS) {
        const int gx = gridDim.x;
        const int nwg = gx * gridDim.y;
        const int lin = by * gx + bx;
        const int logical = (lin & 7) * (nwg >> 3) + (lin >> 3);
        bx = logical % gx;
        by = logical / gx;
    }
    const int row0 = (SW ? bx : by) * BM;
    const int col0 = (SW ? by : bx) * BN;

    f32x4 acc[FM][FN];
    #pragma unroll
    for (int i = 0; i < FM; ++i)
        #pragma unroll
        for (int j = 0; j < FN; ++j)
            acc[i][j] = (f32x4){0.f, 0.f, 0.f, 0.f};

    const int srow = (lane >> 3);
    const int scol = ((lane & 7) ^ srow) * 8;   // pre-swizzled source chunk (T21)

    for (int kk = 0; kk < K; kk += 64) {
        #pragma unroll
        for (int i = 0; i < BM / 32; ++i)
            gld16(A + (size_t)(row0 + i * 32 + wid * 8 + srow) * K + kk + scol,
                  &Al[(i * 32 + wid * 8) * 64]);
        #pragma unroll
        for (int i = 0; i < BN / 32; ++i)
            gld16(Bt + (size_t)(col0 + i * 32 + wid * 8 + srow) * K + kk + scol,
                  &Bl[(i * 32 + wid * 8) * 64]);
        __syncthreads();

        #pragma unroll
        for (int kc = 0; kc < 2; ++kc) {
            short8 af[FM], bfr[FN];
            #pragma unroll
            for (int i = 0; i < FM; ++i) {
                const int row = wr * WM + i * 16 + lrow;
                af[i] = *(const short8*)((const char*)Al + row * 128
                          + ((kc * 64 + kq * 16) ^ ((row & 7) << 4)));
            }
            #pragma unroll
            for (int j = 0; j < FN; ++j) {
                const int row = wc * WN + j * 16 + lrow;
                bfr[j] = *(const short8*)((const char*)Bl + row * 128
                          + ((kc * 64 + kq * 16) ^ ((row & 7) << 4)));
            }
            #pragma unroll
            for (int i = 0; i < FM; ++i)
                #pragma unroll
                for (int j = 0; j < FN; ++j)
                    acc[i][j] = __builtin_amdgcn_mfma_f32_16x16x32_bf16(af[i], bfr[j], acc[i][j], 0, 0, 0);
        }
        __syncthreads();
    }

    #pragma unroll
    for (int i = 0; i < FM; ++i)
        #pragma unroll
        for (int j = 0; j < FN; ++j) {
            const int col = col0 + wc * WN + j * 16 + lrow;
            const float bv = bias[col];
            const int rowq = row0 + wr * WM + i * 16 + kq * 4;
            if (WVT && col >= 1536) {
                const int cv = col - 1536;
                const int bh = (rowq >> 10) * H_ + (cv >> 6);
                store_bf4(&vTp[((size_t)bh * DH_ + (cv & 63)) * S_ + (rowq & 1023)],
                          acc[i][j][0] + bv, acc[i][j][1] + bv,
                          acc[i][j][2] + bv, acc[i][j][3] + bv);
            } else {
                #pragma unroll
                for (int r = 0; r < 4; ++r) {
                    const int row = rowq + r;
                    float vv = acc[i][j][r] + bv;
                    if (ACT == 1) vv = 0.5f * vv * (1.0f + erff(vv * 0.70710678118654752f));
                    if (WVT && col < D_) vv *= 0.03608439182435161f;  // fold attn scale into Q
                    if (WF32) Cf[(size_t)row * N + col] = vv;
                    if (WBF) {
                        if (NT) __builtin_nontemporal_store(f2b(vv),
                                    (unsigned short*)&Cb[(size_t)row * ldcb + col]);
                        else    Cb[(size_t)row * ldcb + col] = __float2bfloat16(vv);
                    }
                }
            }
        }
}

// ---------------- legacy f32 GEMM (fallback for logits if no workspace) ----------------
__global__ __launch_bounds__(256) void gemm_k(const float* __restrict__ A,
                                              const float* __restrict__ W,
                                              const float* __restrict__ bias,
                                              float* __restrict__ Cout,
                                              int M, int N, int K) {
    __shared__ float As[64][16];
    __shared__ float Bs[16][64];
    const int tid = threadIdx.x;
    const int tx = tid & 15, ty = tid >> 4;
    const int row0 = blockIdx.y * 64, col0 = blockIdx.x * 64;
    float acc[4][4] = {};

    for (int kk = 0; kk < K; kk += 16) {
        #pragma unroll
        for (int it = 0; it < 4; ++it) {
            int idx = tid + it * 256;
            int m = idx >> 4, k = idx & 15;
            As[m][k] = A[(size_t)(row0 + m) * K + kk + k];
            int r = idx >> 6, c = idx & 63;
            Bs[r][c] = W[(size_t)(kk + r) * N + col0 + c];
        }
        __syncthreads();
        #pragma unroll
        for (int k = 0; k < 16; ++k) {
            float a[4], b[4];
            #pragma unroll
            for (int i = 0; i < 4; ++i) a[i] = As[ty * 4 + i][k];
            #pragma unroll
            for (int j = 0; j < 4; ++j) b[j] = Bs[k][tx * 4 + j];
            #pragma unroll
            for (int i = 0; i < 4; ++i)
                #pragma unroll
                for (int j = 0; j < 4; ++j)
                    acc[i][j] += a[i] * b[j];
        }
        __syncthreads();
    }

    #pragma unroll
    for (int i = 0; i < 4; ++i) {
        int r = row0 + ty * 4 + i;
        #pragma unroll
        for (int j = 0; j < 4; ++j) {
            int c = col0 + tx * 4 + j;
            Cout[(size_t)r * N + c] = acc[i][j] + bias[c];
        }
    }
}

// ---------------- MFMA flash attention, double-buffered KV + defer-rescale (T3+T13) ----------------
// KVB=128 (measured-best; KVB=64 occupancy experiment regressed, r14).
__global__ __launch_bounds__(256) void fattn_k(const __hip_bfloat16* __restrict__ qkv,
                                               const __hip_bfloat16* __restrict__ vT,
                                               __hip_bfloat16* __restrict__ o) {
    const int qt0 = blockIdx.x * 64;
    const int bh = blockIdx.y;
    const int b = bh / H_, hh = bh % H_;
    const size_t rb = (size_t)b * S_;
    const int hoff = hh * DH_;

    __shared__ __hip_bfloat16 Ks[2][KVB_ * 64];   // 2 x 16 KB
    __shared__ __hip_bfloat16 Vt[2][64 * KVB_];   // 2 x 16 KB
    __shared__ __hip_bfloat16 Ps[64 * KVB_];      // 16 KB

    const int tid = threadIdx.x;
    const int w = tid >> 6, lane = tid & 63;
    const int lr = lane & 15, lk = lane >> 4;
    const size_t vbase = (size_t)bh * DH_ * S_;

    short8 aq[2];
    {
        const int qrow = qt0 + w * 16 + lr;
        #pragma unroll
        for (int kc = 0; kc < 2; ++kc)
            aq[kc] = *(const short8*)&qkv[(rb + qrow) * NQKV_ + hoff + kc * 32 + lk * 8];
    }

    f32x4 oacc[4];
    float m_i[4], l_i[4];
    #pragma unroll
    for (int r = 0; r < 4; ++r) {
        oacc[r] = (f32x4){0.f, 0.f, 0.f, 0.f};
        m_i[r] = -1e30f;
        l_i[r] = 0.f;
    }

    auto stage = [&](int bi, int kt0) {
        #pragma unroll
        for (int t = 0; t < 4; ++t) {
            const int r0 = w * 32 + t * 8;
            const int r = r0 + (lane >> 3);
            const int cs = (lane & 7) ^ ((r & 7) ^ ((r >> 3) & 7));
            gld16(&qkv[(rb + kt0 + r) * NQKV_ + D_ + hoff + cs * 8], &Ks[bi][r0 * 64]);
        }
        #pragma unroll
        for (int t = 0; t < 4; ++t) {
            const int d0 = w * 16 + t * 4;
            const int d = d0 + (lane >> 4);
            const int cs = (lane & 15) ^ (d & 15);
            gld16(&vT[vbase + (size_t)d * S_ + kt0 + cs * 8], &Vt[bi][d0 * 128]);
        }
    };

    stage(0, 0);                                   // prologue
    int cur = 0;
    for (int kt0 = 0; kt0 < S_; kt0 += KVB_) {
        __syncthreads();                           // buf[cur] loads drained; prev compute done
        if (kt0 + KVB_ < S_) stage(cur ^ 1, kt0 + KVB_);   // overlap next-tile loads w/ compute
        const char* Kb = (const char*)Ks[cur];
        const char* Vb = (const char*)Vt[cur];

        // ---- scores S = Q @ K^T (Q pre-scaled in QKV epilogue) ----
        f32x4 s[8];
        #pragma unroll
        for (int j = 0; j < 8; ++j) s[j] = (f32x4){0.f, 0.f, 0.f, 0.f};
        __builtin_amdgcn_s_setprio(1);
        #pragma unroll
        for (int kc = 0; kc < 2; ++kc) {
            #pragma unroll
            for (int j = 0; j < 8; ++j) {
                int kr = j * 16 + lr;
                short8 bk = *(const short8*)(Kb + kr * 128
                              + ((kc * 64 + lk * 16) ^ ((((kr & 7) ^ ((kr >> 3) & 7)) << 4))));
                s[j] = __builtin_amdgcn_mfma_f32_16x16x32_bf16(aq[kc], bk, s[j], 0, 0, 0);
            }
        }
        __builtin_amdgcn_s_setprio(0);

        // ---- online softmax with defer-rescale (T13, THR=8) ----
        float tmax[4];
        #pragma unroll
        for (int r = 0; r < 4; ++r) {
            float t = s[0][r];
            #pragma unroll
            for (int j = 1; j < 8; ++j) t = fmaxf(t, s[j][r]);
            tmax[r] = t;
        }
        float excess = fmaxf(fmaxf(tmax[0] - m_i[0], tmax[1] - m_i[1]),
                             fmaxf(tmax[2] - m_i[2], tmax[3] - m_i[3]));
        if (!__all(excess <= 8.0f)) {
            #pragma unroll
            for (int r = 0; r < 4; ++r) {
                float tm = tmax[r];
                #pragma unroll
                for (int off = 1; off <= 8; off <<= 1)
                    tm = fmaxf(tm, __shfl_xor(tm, off));
                float mnew = fmaxf(m_i[r], tm);
                float corr = __expf(m_i[r] - mnew);
                m_i[r] = mnew;
                l_i[r] *= corr;
                #pragma unroll
                for (int jd = 0; jd < 4; ++jd) oacc[jd][r] *= corr;
            }
        }
        #pragma unroll
        for (int r = 0; r < 4; ++r) {
            float psum = 0.f;
            const int prow = w * 16 + lk * 4 + r;
            #pragma unroll
            for (int j = 0; j < 8; ++j) {
                float p = __expf(s[j][r] - m_i[r]);     // bounded by e^8
                psum += p;
                *(__hip_bfloat16*)((char*)Ps + prow * 256
                    + (((j * 16 + lr) * 2) ^ ((prow & 15) << 4))) = __float2bfloat16(p);
            }
            #pragma unroll
            for (int off = 1; off <= 8; off <<= 1)
                psum += __shfl_xor(psum, off);
            l_i[r] += psum;
        }

        // ---- PV: O += P @ V (Ps rows wave-private) ----
        __builtin_amdgcn_s_setprio(1);
        #pragma unroll
        for (int ks = 0; ks < 4; ++ks) {
            const int prow = w * 16 + lr;
            short8 pa = *(const short8*)((const char*)Ps + prow * 256
                          + ((ks * 64 + lk * 16) ^ ((prow & 15) << 4)));
            #pragma unroll
            for (int jd = 0; jd < 4; ++jd) {
                int vr = jd * 16 + lr;
                short8 vb = *(const short8*)(Vb + vr * 256
                              + ((ks * 64 + lk * 16) ^ ((vr & 15) << 4)));
                oacc[jd] = __builtin_amdgcn_mfma_f32_16x16x32_bf16(pa, vb, oacc[jd], 0, 0, 0);
            }
        }
        __builtin_amdgcn_s_setprio(0);
        cur ^= 1;
    }

    #pragma unroll
    for (int r = 0; r < 4; ++r) {
        float inv = 1.0f / l_i[r];
        const int row = qt0 + w * 16 + lk * 4 + r;
        #pragma unroll
        for (int jd = 0; jd < 4; ++jd)
            o[(rb + row) * (size_t)D_ + hoff + jd * 16 + lr] = __float2bfloat16(oacc[jd][r] * inv);
    }
}

// ---------------- add + layernorm; single-pass wave-reduce (1 barrier) ----------------
__global__ __launch_bounds__(256) void addln_k(const float* __restrict__ a,
                                               const float* __restrict__ b,
                                               const float* __restrict__ g,
                                               const float* __restrict__ beta,
                                               float* __restrict__ out,
                                               __hip_bfloat16* __restrict__ out_bf) {
    const int r = blockIdx.x;
    const int tid = threadIdx.x;
    const int wid = tid >> 6, lane = tid & 63;
    __shared__ float w1[4], w2[4];
    float xv[3];
    float s1 = 0.f, s2 = 0.f;
    #pragma unroll
    for (int i = 0; i < 3; ++i) {
        int d = tid + i * 256;
        xv[i] = a[(size_t)r * D_ + d] + b[(size_t)r * D_ + d];
        s1 += xv[i];
        s2 += xv[i] * xv[i];
    }
    #pragma unroll
    for (int off = 1; off <= 32; off <<= 1) {
        s1 += __shfl_xor(s1, off);
        s2 += __shfl_xor(s2, off);
    }
    if (lane == 0) { w1[wid] = s1; w2[wid] = s2; }
    __syncthreads();
    s1 = w1[0] + w1[1] + w1[2] + w1[3];
    s2 = w2[0] + w2[1] + w2[2] + w2[3];
    float mu = s1 * (1.0f / D_);
    float var = s2 * (1.0f / D_) - mu * mu;
    float rstd = rsqrtf(var + 1e-5f);
    #pragma unroll
    for (int i = 0; i < 3; ++i) {
        int d = tid + i * 256;
        float v = (xv[i] - mu) * rstd * g[d] + beta[d];
        out[(size_t)r * D_ + d] = v;
        out_bf[(size_t)r * D_ + d] = __float2bfloat16(v);
    }
}

// ---------------- log-softmax fallback (f32 logits in place) ----------------
__global__ __launch_bounds__(256) void lsm_k(float* __restrict__ lp) {
    const int r = blockIdx.x;
    const int tid = threadIdx.x;
    const int wid = tid >> 6, lane = tid & 63;
    __shared__ float wm[4], wl[4];
    float* row = lp + (size_t)r * V_;
    float mt = -1e30f, lt = 0.f;
    for (int i = tid * 4; i < V_; i += 1024) {
        float4 v = *(const float4*)&row[i];
        float c = fmaxf(fmaxf(v.x, v.y), fmaxf(v.z, v.w));
        if (c > mt) { lt *= __expf(mt - c); mt = c; }
        lt += __expf(v.x - mt) + __expf(v.y - mt) + __expf(v.z - mt) + __expf(v.w - mt);
    }
    #pragma unroll
    for (int off = 1; off <= 32; off <<= 1) {
        float m2 = __shfl_xor(mt, off), l2 = __shfl_xor(lt, off);
        float M = fmaxf(mt, m2);
        lt = lt * __expf(mt - M) + l2 * __expf(m2 - M);
        mt = M;
    }
    if (lane == 0) { wm[wid] = mt; wl[wid] = lt; }
    __syncthreads();
    float M4 = fmaxf(fmaxf(wm[0], wm[1]), fmaxf(wm[2], wm[3]));
    float L4 = wl[0] * __expf(wm[0] - M4) + wl[1] * __expf(wm[1] - M4)
             + wl[2] * __expf(wm[2] - M4) + wl[3] * __expf(wm[3] - M4);
    float sub = M4 + __logf(L4);
    for (int i = tid * 4; i < V_; i += 1024) {
        float4 v = *(const float4*)&row[i];
        v.x -= sub; v.y -= sub; v.z -= sub; v.w -= sub;
        *(float4*)&row[i] = v;
    }
}

// ---------------- log-softmax from bf16 logits, expanding in place to f32 ----------------
// Row r's bf16 logits occupy the FRONT HALF of row r's f32 slot range (ldcb = 2V).
// Descending-chunk in-place expansion; tail chunk predicated (V % 2048 != 0).
// Output f32 writes are non-temporal (never re-read on device; keeps upcoming
// bf16 reads resident in L2).
__global__ __launch_bounds__(256) void lsmx_k(float* __restrict__ lp) {
    const int r = blockIdx.x;
    const int tid = threadIdx.x;
    const int wid = tid >> 6, lane = tid & 63;
    __shared__ float wm[4], wl[4];
    float* row = lp + (size_t)r * V_;
    const __hip_bfloat16* brow = (const __hip_bfloat16*)row;

    float mt = -1e30f, lt = 0.f;
    for (int i = tid * 8; i < V_; i += 2048) {
        short8 v = *(const short8*)&brow[i];
        #pragma unroll
        for (int j = 0; j < 8; ++j) {
            float f = b2f((unsigned short)v[j]);
            if (f > mt) { lt *= __expf(mt - f); mt = f; }
            lt += __expf(f - mt);
        }
    }
    #pragma unroll
    for (int off = 1; off <= 32; off <<= 1) {
        float m2 = __shfl_xor(mt, off), l2 = __shfl_xor(lt, off);
        float M = fmaxf(mt, m2);
        lt = lt * __expf(mt - M) + l2 * __expf(m2 - M);
        mt = M;
    }
    if (lane == 0) { wm[wid] = mt; wl[wid] = lt; }
    __syncthreads();
    float M4 = fmaxf(fmaxf(wm[0], wm[1]), fmaxf(wm[2], wm[3]));
    float L4 = wl[0] * __expf(wm[0] - M4) + wl[1] * __expf(wm[1] - M4)
             + wl[2] * __expf(wm[2] - M4) + wl[3] * __expf(wm[3] - M4);
    float sub = M4 + __logf(L4);

    for (int ci = 15; ci >= 0; --ci) {
        const int c = ci * 2048 + tid * 8;
        const bool act = (c < V_);            // tail guard: V not a multiple of 2048
        short8 v;
        if (act) v = *(const short8*)&brow[c];
        __syncthreads();                      // all reads of this chunk done before writes
        if (act) {
            f32x4 o0, o1;
            o0[0] = b2f((unsigned short)v[0]) - sub;
            o0[1] = b2f((unsigned short)v[1]) - sub;
            o0[2] = b2f((unsigned short)v[2]) - sub;
            o0[3] = b2f((unsigned short)v[3]) - sub;
            o1[0] = b2f((unsigned short)v[4]) - sub;
            o1[1] = b2f((unsigned short)v[5]) - sub;
            o1[2] = b2f((unsigned short)v[6]) - sub;
            o1[3] = b2f((unsigned short)v[7]) - sub;
            __builtin_nontemporal_store(o0, (f32x4*)&row[c]);
            __builtin_nontemporal_store(o1, (f32x4*)&row[c + 4]);
        }
    }
}

extern "C" void kernel_launch(void* const* d_in, const int* in_sizes, int n_in,
                              void* d_out, int out_size, void* d_ws, size_t ws_size,
                              hipStream_t stream) {
    const int*   x    = (const int*)  d_in[0];
    const float* tok  = (const float*)d_in[1];
    const float* pos  = (const float*)d_in[2];
    const float* Wq   = (const float*)d_in[3];
    const float* bq   = (const float*)d_in[4];
    const float* Wk   = (const float*)d_in[5];
    const float* bk   = (const float*)d_in[6];
    const float* Wv   = (const float*)d_in[7];
    const float* bv   = (const float*)d_in[8];
    const float* Wo   = (const float*)d_in[9];
    const float* bo   = (const float*)d_in[10];
    const float* ln1g = (const float*)d_in[11];
    const float* ln1b = (const float*)d_in[12];
    const float* W1   = (const float*)d_in[13];
    const float* b1   = (const float*)d_in[14];
    const float* W2   = (const float*)d_in[15];
    const float* b2   = (const float*)d_in[16];
    const float* ln2g = (const float*)d_in[17];
    const float* ln2b = (const float*)d_in[18];
    const float* Wf   = (const float*)d_in[19];
    const float* bff  = (const float*)d_in[20];

    float* out = (float*)d_out;
    const size_t HS = (size_t)BS_ * D_;              // 1,572,864

    // f32-slot layout inside logits scratch region [0, BS_*V_):
    __hip_bfloat16* qkv_bf = (__hip_bfloat16*)out;               // BS*2304 bf16
    __hip_bfloat16* vT     = (__hip_bfloat16*)(out + 2359296);   // BS*768 bf16
    __hip_bfloat16* att_bf = (__hip_bfloat16*)(out + 4718592);
    float* tmp   = out + 5505024;
    float* h1    = out + 7077888;
    __hip_bfloat16* h1_bf  = (__hip_bfloat16*)(out + 8650752);
    __hip_bfloat16* ff_bf  = (__hip_bfloat16*)(out + 9437184);
    __hip_bfloat16* h_bf   = (__hip_bfloat16*)(out + 12582912);
    __hip_bfloat16* Wqkv_t = (__hip_bfloat16*)(out + 13369344);  // 6 x [2304][768]
    __hip_bfloat16* Wo_t   = (__hip_bfloat16*)(out + 18677760);  // 6 x [768][768]
    __hip_bfloat16* W1_t   = (__hip_bfloat16*)(out + 20447232);  // 6 x [3072][768]
    __hip_bfloat16* W2_t   = (__hip_bfloat16*)(out + 27525120);  // 6 x [768][3072]
    float* bqkv  = out + 34603008;                   // 6 x 2304
    float* h     = out + (size_t)BS_ * V_;           // tail: hset output

    const bool ws_ok = ws_size >= 52297728ULL;       // Wf_t (49.15MB) + hbf (3.15MB)
    __hip_bfloat16* Wf_t   = (__hip_bfloat16*)d_ws;              // [32000][768]
    __hip_bfloat16* hbf_ws = (__hip_bfloat16*)((char*)d_ws + 49152000);

    // ---- weight transpose/convert pre-pass ----
    const size_t DD = (size_t)D_ * D_, DF = (size_t)D_ * F_;
    const size_t QKVL = (size_t)NQKV_ * D_;
    qkvt_k<<<dim3(D_/32, D_/32, 3 * L_), 256, 0, stream>>>(Wq, Wk, Wv, Wqkv_t);
    transp_k<<<dim3(D_/32, D_/32, L_), 256, 0, stream>>>(Wo, DD, Wo_t, DD,   D_, D_);
    transp_k<<<dim3(F_/32, D_/32, L_), 256, 0, stream>>>(W1, DF, W1_t, DF,   F_, D_);
    transp_k<<<dim3(D_/32, F_/32, L_), 256, 0, stream>>>(W2, DF, W2_t, DF,   D_, F_);
    bcat_k<<<L_, 256, 0, stream>>>(bq, bk, bv, bqkv);
    if (ws_ok)
        transp_k<<<dim3(V_/32, D_/32, 1), 256, 0, stream>>>(Wf, 0, Wf_t, 0, V_, D_);

    embed_k<<<BS_, 256, 0, stream>>>(x, tok, pos, h, h_bf);

    const dim3 gQKV(NQKV_/128, BS_/64);    // (18, 32) -> 576 blocks (BM=64)
    const dim3 gFF1(F_/128,    BS_/64);    // (24, 32) -> 768 blocks (BM=64)
    const dim3 gOUT64(D_/64,   BS_/64);    // (12, 32) -> 384 blocks
    const dim3 gA(S_/64, B_*H_);           // (16, 24)
    for (int i = 0; i < L_; ++i) {
        mgemm_k<64,128,0,false,true,false,false,true,false><<<gQKV, 256, 0, stream>>>(
            h_bf, Wqkv_t + (size_t)i * QKVL, bqkv + (size_t)i * NQKV_, nullptr, qkv_bf, vT, BS_, NQKV_, D_, NQKV_);
        fattn_k<<<gA, 256, 0, stream>>>(qkv_bf, vT, att_bf);
        mgemm_k<64,64,0,true,false,false,false,false,false><<<gOUT64, 256, 0, stream>>>(
            att_bf, Wo_t + (size_t)i * DD, bo + (size_t)i * D_, tmp, nullptr, nullptr, BS_, D_, D_, D_);
        addln_k<<<BS_, 256, 0, stream>>>(tmp, h, ln1g + (size_t)i * D_, ln1b + (size_t)i * D_, h1, h1_bf);
        mgemm_k<64,128,1,false,true,false,false,false,false><<<gFF1, 256, 0, stream>>>(
            h1_bf, W1_t + (size_t)i * DF, b1 + (size_t)i * F_, nullptr, ff_bf, nullptr, BS_, F_, D_, F_);
        mgemm_k<64,64,0,true,false,false,false,false,false><<<gOUT64, 256, 0, stream>>>(
            ff_bf, W2_t + (size_t)i * DF, b2 + (size_t)i * D_, tmp, nullptr, nullptr, BS_, D_, F_, D_);
        // last layer's bf16 hset goes straight to the logits-GEMM input buffer (skips cvt)
        __hip_bfloat16* obf = (i == L_ - 1 && ws_ok) ? hbf_ws : h_bf;
        addln_k<<<BS_, 256, 0, stream>>>(tmp, h1, ln2g + (size_t)i * D_, ln2b + (size_t)i * D_, h, obf);
    }

    if (ws_ok) {
        // bf16 logits parked at the front half of each output row (ldcb = 2V), NT stores;
        // then lsmx expands in place to f32 log-probs (NT output stream).
        mgemm_k<128,128,0,false,true,true,true,false,true><<<dim3(BS_/128, V_/128), 256, 0, stream>>>(
            hbf_ws, Wf_t, bff, nullptr, (__hip_bfloat16*)out, nullptr, BS_, V_, D_, 2 * V_);
        lsmx_k<<<BS_, 256, 0, stream>>>(out);
    } else {
        gemm_k<<<dim3(V_/64, BS_/64), 256, 0, stream>>>(h, Wf, bff, out, BS_, V_, D_);
        lsm_k<<<BS_, 256, 0, stream>>>(out);
    }
}

// Round 18
// 1097.040 us; speedup vs baseline: 1.0290x; 1.0015x over previous
//
#include <hip/hip_runtime.h>
#include <hip/hip_bf16.h>
#include <math.h>

#define B_ 2
#define S_ 1024
#define V_ 32000
#define D_ 768
#define F_ 3072
#define H_ 12
#define L_ 6
#define DH_ 64
#define BS_ (B_*S_)   // 2048
#define NQKV_ 2304
#define KVB_ 128

typedef __attribute__((ext_vector_type(8))) short short8;
typedef __attribute__((ext_vector_type(4))) float f32x4;

__device__ __forceinline__ unsigned short f2b(float f) {
    union { __hip_bfloat16 h; unsigned short u; } cv;
    cv.h = __float2bfloat16(f);
    return cv.u;
}

__device__ __forceinline__ float b2f(unsigned short u) {
    union { unsigned int i; float f; } cv;
    cv.i = ((unsigned int)u) << 16;
    return cv.f;
}

__device__ __forceinline__ void store_bf4(__hip_bfloat16* p, float a, float b, float c, float d) {
    unsigned long long pk = (unsigned long long)f2b(a)
        | ((unsigned long long)f2b(b) << 16)
        | ((unsigned long long)f2b(c) << 32)
        | ((unsigned long long)f2b(d) << 48);
    *(unsigned long long*)p = pk;
}

__device__ __forceinline__ void gld16(const void* g, void* l) {
    __builtin_amdgcn_global_load_lds(
        (const __attribute__((address_space(1))) unsigned int*)g,
        (__attribute__((address_space(3))) unsigned int*)l,
        16, 0, 0);
}

// ---------------- embedding (dual write f32 + bf16) ----------------
__global__ void embed_k(const int* __restrict__ x, const float* __restrict__ tok,
                        const float* __restrict__ pos, float* __restrict__ h,
                        __hip_bfloat16* __restrict__ hbf) {
    int bs = blockIdx.x;
    int s = bs % S_;
    int t = x[bs];
    for (int d = threadIdx.x; d < D_; d += blockDim.x) {
        float v = tok[(size_t)t * D_ + d] + pos[(size_t)s * D_ + d];
        h[(size_t)bs * D_ + d] = v;
        hbf[(size_t)bs * D_ + d] = __float2bfloat16(v);
    }
}

// ---------------- transpose+convert: src f32 [K][N] -> dst bf16 [N][K] ----------------
__global__ __launch_bounds__(256) void transp_k(const float* __restrict__ src, size_t sl,
                                                __hip_bfloat16* __restrict__ dst, size_t dl,
                                                int N, int K) {
    const float* S = src + (size_t)blockIdx.z * sl;
    __hip_bfloat16* Dp = dst + (size_t)blockIdx.z * dl;
    __shared__ float T[32][33];
    const int k0 = blockIdx.y * 32, n0 = blockIdx.x * 32;
    const int tid = threadIdx.x;
    const int r = tid >> 3, c4 = (tid & 7) * 4;
    float4 vv = *(const float4*)&S[(size_t)(k0 + r) * N + n0 + c4];
    T[r][c4 + 0] = vv.x; T[r][c4 + 1] = vv.y; T[r][c4 + 2] = vv.z; T[r][c4 + 3] = vv.w;
    __syncthreads();
    store_bf4(&Dp[(size_t)(n0 + r) * K + k0 + c4],
              T[c4 + 0][r], T[c4 + 1][r], T[c4 + 2][r], T[c4 + 3][r]);
}

// ---------------- fused Wq/Wk/Wv transpose: z = layer*3 + which ----------------
__global__ __launch_bounds__(256) void qkvt_k(const float* __restrict__ Wq,
                                              const float* __restrict__ Wk,
                                              const float* __restrict__ Wv,
                                              __hip_bfloat16* __restrict__ Wqkv_t) {
    const int zi = blockIdx.z;
    const int layer = zi / 3, which = zi % 3;
    const size_t DD = (size_t)D_ * D_;
    const float* S = (which == 0 ? Wq : which == 1 ? Wk : Wv) + (size_t)layer * DD;
    __hip_bfloat16* Dp = Wqkv_t + (size_t)layer * ((size_t)NQKV_ * D_) + (size_t)which * DD;
    __shared__ float T[32][33];
    const int k0 = blockIdx.y * 32, n0 = blockIdx.x * 32;
    const int tid = threadIdx.x;
    const int r = tid >> 3, c4 = (tid & 7) * 4;
    float4 vv = *(const float4*)&S[(size_t)(k0 + r) * D_ + n0 + c4];
    T[r][c4 + 0] = vv.x; T[r][c4 + 1] = vv.y; T[r][c4 + 2] = vv.z; T[r][c4 + 3] = vv.w;
    __syncthreads();
    store_bf4(&Dp[(size_t)(n0 + r) * D_ + k0 + c4],
              T[c4 + 0][r], T[c4 + 1][r], T[c4 + 2][r], T[c4 + 3][r]);
}

// ---------------- concat qkv biases ----------------
__global__ void bcat_k(const float* __restrict__ bq, const float* __restrict__ bk,
                       const float* __restrict__ bv, float* __restrict__ dst) {
    int l = blockIdx.x;
    for (int j = threadIdx.x; j < D_; j += blockDim.x) {
        dst[(size_t)l * NQKV_ + j]          = bq[(size_t)l * D_ + j];
        dst[(size_t)l * NQKV_ + D_ + j]     = bk[(size_t)l * D_ + j];
        dst[(size_t)l * NQKV_ + 2 * D_ + j] = bv[(size_t)l * D_ + j];
    }
}

// ---------------- MFMA bf16 GEMM: C = act(A[M,K] @ Bt[N,K]^T + bias [+ Res]) ----------------
// LDS tiles XOR-swizzled (T2). SW: M on blockIdx.x. XS: XCD-bijective swizzle.
// WVT: QKV mode -- V-cols -> vT[bh][d][s], Q-cols pre-scaled. ldcb = bf16 C row
// stride. NT: non-temporal bf16 C stores (logits stream). RES: fuse residual add
// (Cf = acc + bias + Res) so the following LN reads a single input.
template<int BM, int BN, int ACT, bool WF32, bool WBF, bool SW, bool XS, bool WVT, bool NT, bool RES>
__global__ __launch_bounds__(256) void mgemm_k(const __hip_bfloat16* __restrict__ A,
                                               const __hip_bfloat16* __restrict__ Bt,
                                               const float* __restrict__ bias,
                                               float* __restrict__ Cf,
                                               __hip_bfloat16* __restrict__ Cb,
                                               __hip_bfloat16* __restrict__ vTp,
                                               const float* __restrict__ Res,
                                               int M, int N, int K, int ldcb) {
    constexpr int WM = BM / 2, WN = BN / 2;
    constexpr int FM = WM / 16, FN = WN / 16;
    __shared__ __hip_bfloat16 Al[BM * 64];
    __shared__ __hip_bfloat16 Bl[BN * 64];
    const int tid = threadIdx.x;
    const int wid = tid >> 6, lane = tid & 63;
    const int wr = wid >> 1, wc = wid & 1;
    const int lrow = lane & 15, kq = lane >> 4;

    int bx = blockIdx.x, by = blockIdx.y;
    if (XS) {
        const int gx = gridDim.x;
        const int nwg = gx * gridDim.y;
        const int lin = by * gx + bx;
        const int logical = (lin & 7) * (nwg >> 3) + (lin >> 3);
        bx = logical % gx;
        by = logical / gx;
    }
    const int row0 = (SW ? bx : by) * BM;
    const int col0 = (SW ? by : bx) * BN;

    f32x4 acc[FM][FN];
    #pragma unroll
    for (int i = 0; i < FM; ++i)
        #pragma unroll
        for (int j = 0; j < FN; ++j)
            acc[i][j] = (f32x4){0.f, 0.f, 0.f, 0.f};

    const int srow = (lane >> 3);
    const int scol = ((lane & 7) ^ srow) * 8;   // pre-swizzled source chunk (T21)

    for (int kk = 0; kk < K; kk += 64) {
        #pragma unroll
        for (int i = 0; i < BM / 32; ++i)
            gld16(A + (size_t)(row0 + i * 32 + wid * 8 + srow) * K + kk + scol,
                  &Al[(i * 32 + wid * 8) * 64]);
        #pragma unroll
        for (int i = 0; i < BN / 32; ++i)
            gld16(Bt + (size_t)(col0 + i * 32 + wid * 8 + srow) * K + kk + scol,
                  &Bl[(i * 32 + wid * 8) * 64]);
        __syncthreads();

        #pragma unroll
        for (int kc = 0; kc < 2; ++kc) {
            short8 af[FM], bfr[FN];
            #pragma unroll
            for (int i = 0; i < FM; ++i) {
                const int row = wr * WM + i * 16 + lrow;
                af[i] = *(const short8*)((const char*)Al + row * 128
                          + ((kc * 64 + kq * 16) ^ ((row & 7) << 4)));
            }
            #pragma unroll
            for (int j = 0; j < FN; ++j) {
                const int row = wc * WN + j * 16 + lrow;
                bfr[j] = *(const short8*)((const char*)Bl + row * 128
                          + ((kc * 64 + kq * 16) ^ ((row & 7) << 4)));
            }
            #pragma unroll
            for (int i = 0; i < FM; ++i)
                #pragma unroll
                for (int j = 0; j < FN; ++j)
                    acc[i][j] = __builtin_amdgcn_mfma_f32_16x16x32_bf16(af[i], bfr[j], acc[i][j], 0, 0, 0);
        }
        __syncthreads();
    }

    #pragma unroll
    for (int i = 0; i < FM; ++i)
        #pragma unroll
        for (int j = 0; j < FN; ++j) {
            const int col = col0 + wc * WN + j * 16 + lrow;
            const float bv = bias[col];
            const int rowq = row0 + wr * WM + i * 16 + kq * 4;
            if (WVT && col >= 1536) {
                const int cv = col - 1536;
                const int bh = (rowq >> 10) * H_ + (cv >> 6);
                store_bf4(&vTp[((size_t)bh * DH_ + (cv & 63)) * S_ + (rowq & 1023)],
                          acc[i][j][0] + bv, acc[i][j][1] + bv,
                          acc[i][j][2] + bv, acc[i][j][3] + bv);
            } else {
                #pragma unroll
                for (int r = 0; r < 4; ++r) {
                    const int row = rowq + r;
                    float vv = acc[i][j][r] + bv;
                    if (ACT == 1) vv = 0.5f * vv * (1.0f + erff(vv * 0.70710678118654752f));
                    if (WVT && col < D_) vv *= 0.03608439182435161f;  // fold attn scale into Q
                    if (RES)  vv += Res[(size_t)row * N + col];       // fused residual add
                    if (WF32) Cf[(size_t)row * N + col] = vv;
                    if (WBF) {
                        if (NT) __builtin_nontemporal_store(f2b(vv),
                                    (unsigned short*)&Cb[(size_t)row * ldcb + col]);
                        else    Cb[(size_t)row * ldcb + col] = __float2bfloat16(vv);
                    }
                }
            }
        }
}

// ---------------- legacy f32 GEMM (fallback for logits if no workspace) ----------------
__global__ __launch_bounds__(256) void gemm_k(const float* __restrict__ A,
                                              const float* __restrict__ W,
                                              const float* __restrict__ bias,
                                              float* __restrict__ Cout,
                                              int M, int N, int K) {
    __shared__ float As[64][16];
    __shared__ float Bs[16][64];
    const int tid = threadIdx.x;
    const int tx = tid & 15, ty = tid >> 4;
    const int row0 = blockIdx.y * 64, col0 = blockIdx.x * 64;
    float acc[4][4] = {};

    for (int kk = 0; kk < K; kk += 16) {
        #pragma unroll
        for (int it = 0; it < 4; ++it) {
            int idx = tid + it * 256;
            int m = idx >> 4, k = idx & 15;
            As[m][k] = A[(size_t)(row0 + m) * K + kk + k];
            int r = idx >> 6, c = idx & 63;
            Bs[r][c] = W[(size_t)(kk + r) * N + col0 + c];
        }
        __syncthreads();
        #pragma unroll
        for (int k = 0; k < 16; ++k) {
            float a[4], b[4];
            #pragma unroll
            for (int i = 0; i < 4; ++i) a[i] = As[ty * 4 + i][k];
            #pragma unroll
            for (int j = 0; j < 4; ++j) b[j] = Bs[k][tx * 4 + j];
            #pragma unroll
            for (int i = 0; i < 4; ++i)
                #pragma unroll
                for (int j = 0; j < 4; ++j)
                    acc[i][j] += a[i] * b[j];
        }
        __syncthreads();
    }

    #pragma unroll
    for (int i = 0; i < 4; ++i) {
        int r = row0 + ty * 4 + i;
        #pragma unroll
        for (int j = 0; j < 4; ++j) {
            int c = col0 + tx * 4 + j;
            Cout[(size_t)r * N + c] = acc[i][j] + bias[c];
        }
    }
}

// ---------------- MFMA flash attention, double-buffered KV + defer-rescale (T3+T13) ----------------
// KVB=128 (measured-best; KVB=64 occupancy experiment regressed, r14).
__global__ __launch_bounds__(256) void fattn_k(const __hip_bfloat16* __restrict__ qkv,
                                               const __hip_bfloat16* __restrict__ vT,
                                               __hip_bfloat16* __restrict__ o) {
    const int qt0 = blockIdx.x * 64;
    const int bh = blockIdx.y;
    const int b = bh / H_, hh = bh % H_;
    const size_t rb = (size_t)b * S_;
    const int hoff = hh * DH_;

    __shared__ __hip_bfloat16 Ks[2][KVB_ * 64];   // 2 x 16 KB
    __shared__ __hip_bfloat16 Vt[2][64 * KVB_];   // 2 x 16 KB
    __shared__ __hip_bfloat16 Ps[64 * KVB_];      // 16 KB

    const int tid = threadIdx.x;
    const int w = tid >> 6, lane = tid & 63;
    const int lr = lane & 15, lk = lane >> 4;
    const size_t vbase = (size_t)bh * DH_ * S_;

    short8 aq[2];
    {
        const int qrow = qt0 + w * 16 + lr;
        #pragma unroll
        for (int kc = 0; kc < 2; ++kc)
            aq[kc] = *(const short8*)&qkv[(rb + qrow) * NQKV_ + hoff + kc * 32 + lk * 8];
    }

    f32x4 oacc[4];
    float m_i[4], l_i[4];
    #pragma unroll
    for (int r = 0; r < 4; ++r) {
        oacc[r] = (f32x4){0.f, 0.f, 0.f, 0.f};
        m_i[r] = -1e30f;
        l_i[r] = 0.f;
    }

    auto stage = [&](int bi, int kt0) {
        #pragma unroll
        for (int t = 0; t < 4; ++t) {
            const int r0 = w * 32 + t * 8;
            const int r = r0 + (lane >> 3);
            const int cs = (lane & 7) ^ ((r & 7) ^ ((r >> 3) & 7));
            gld16(&qkv[(rb + kt0 + r) * NQKV_ + D_ + hoff + cs * 8], &Ks[bi][r0 * 64]);
        }
        #pragma unroll
        for (int t = 0; t < 4; ++t) {
            const int d0 = w * 16 + t * 4;
            const int d = d0 + (lane >> 4);
            const int cs = (lane & 15) ^ (d & 15);
            gld16(&vT[vbase + (size_t)d * S_ + kt0 + cs * 8], &Vt[bi][d0 * 128]);
        }
    };

    stage(0, 0);                                   // prologue
    int cur = 0;
    for (int kt0 = 0; kt0 < S_; kt0 += KVB_) {
        __syncthreads();                           // buf[cur] loads drained; prev compute done
        if (kt0 + KVB_ < S_) stage(cur ^ 1, kt0 + KVB_);   // overlap next-tile loads w/ compute
        const char* Kb = (const char*)Ks[cur];
        const char* Vb = (const char*)Vt[cur];

        // ---- scores S = Q @ K^T (Q pre-scaled in QKV epilogue) ----
        f32x4 s[8];
        #pragma unroll
        for (int j = 0; j < 8; ++j) s[j] = (f32x4){0.f, 0.f, 0.f, 0.f};
        __builtin_amdgcn_s_setprio(1);
        #pragma unroll
        for (int kc = 0; kc < 2; ++kc) {
            #pragma unroll
            for (int j = 0; j < 8; ++j) {
                int kr = j * 16 + lr;
                short8 bk = *(const short8*)(Kb + kr * 128
                              + ((kc * 64 + lk * 16) ^ ((((kr & 7) ^ ((kr >> 3) & 7)) << 4))));
                s[j] = __builtin_amdgcn_mfma_f32_16x16x32_bf16(aq[kc], bk, s[j], 0, 0, 0);
            }
        }
        __builtin_amdgcn_s_setprio(0);

        // ---- online softmax with defer-rescale (T13, THR=8) ----
        float tmax[4];
        #pragma unroll
        for (int r = 0; r < 4; ++r) {
            float t = s[0][r];
            #pragma unroll
            for (int j = 1; j < 8; ++j) t = fmaxf(t, s[j][r]);
            tmax[r] = t;
        }
        float excess = fmaxf(fmaxf(tmax[0] - m_i[0], tmax[1] - m_i[1]),
                             fmaxf(tmax[2] - m_i[2], tmax[3] - m_i[3]));
        if (!__all(excess <= 8.0f)) {
            #pragma unroll
            for (int r = 0; r < 4; ++r) {
                float tm = tmax[r];
                #pragma unroll
                for (int off = 1; off <= 8; off <<= 1)
                    tm = fmaxf(tm, __shfl_xor(tm, off));
                float mnew = fmaxf(m_i[r], tm);
                float corr = __expf(m_i[r] - mnew);
                m_i[r] = mnew;
                l_i[r] *= corr;
                #pragma unroll
                for (int jd = 0; jd < 4; ++jd) oacc[jd][r] *= corr;
            }
        }
        #pragma unroll
        for (int r = 0; r < 4; ++r) {
            float psum = 0.f;
            const int prow = w * 16 + lk * 4 + r;
            #pragma unroll
            for (int j = 0; j < 8; ++j) {
                float p = __expf(s[j][r] - m_i[r]);     // bounded by e^8
                psum += p;
                *(__hip_bfloat16*)((char*)Ps + prow * 256
                    + (((j * 16 + lr) * 2) ^ ((prow & 15) << 4))) = __float2bfloat16(p);
            }
            #pragma unroll
            for (int off = 1; off <= 8; off <<= 1)
                psum += __shfl_xor(psum, off);
            l_i[r] += psum;
        }

        // ---- PV: O += P @ V (Ps rows wave-private) ----
        __builtin_amdgcn_s_setprio(1);
        #pragma unroll
        for (int ks = 0; ks < 4; ++ks) {
            const int prow = w * 16 + lr;
            short8 pa = *(const short8*)((const char*)Ps + prow * 256
                          + ((ks * 64 + lk * 16) ^ ((prow & 15) << 4)));
            #pragma unroll
            for (int jd = 0; jd < 4; ++jd) {
                int vr = jd * 16 + lr;
                short8 vb = *(const short8*)(Vb + vr * 256
                              + ((ks * 64 + lk * 16) ^ ((vr & 15) << 4)));
                oacc[jd] = __builtin_amdgcn_mfma_f32_16x16x32_bf16(pa, vb, oacc[jd], 0, 0, 0);
            }
        }
        __builtin_amdgcn_s_setprio(0);
        cur ^= 1;
    }

    #pragma unroll
    for (int r = 0; r < 4; ++r) {
        float inv = 1.0f / l_i[r];
        const int row = qt0 + w * 16 + lk * 4 + r;
        #pragma unroll
        for (int jd = 0; jd < 4; ++jd)
            o[(rb + row) * (size_t)D_ + hoff + jd * 16 + lr] = __float2bfloat16(oacc[jd][r] * inv);
    }
}

// ---------------- layernorm over pre-added input; dual write f32 + bf16 ----------------
// Input `a` already contains residual sum (fused into the producing GEMM epilogue).
__global__ __launch_bounds__(256) void addln_k(const float* __restrict__ a,
                                               const float* __restrict__ g,
                                               const float* __restrict__ beta,
                                               float* __restrict__ out,
                                               __hip_bfloat16* __restrict__ out_bf) {
    const int r = blockIdx.x;
    const int tid = threadIdx.x;
    const int wid = tid >> 6, lane = tid & 63;
    __shared__ float w1[4], w2[4];
    float xv[3];
    float s1 = 0.f, s2 = 0.f;
    #pragma unroll
    for (int i = 0; i < 3; ++i) {
        int d = tid + i * 256;
        xv[i] = a[(size_t)r * D_ + d];
        s1 += xv[i];
        s2 += xv[i] * xv[i];
    }
    #pragma unroll
    for (int off = 1; off <= 32; off <<= 1) {
        s1 += __shfl_xor(s1, off);
        s2 += __shfl_xor(s2, off);
    }
    if (lane == 0) { w1[wid] = s1; w2[wid] = s2; }
    __syncthreads();
    s1 = w1[0] + w1[1] + w1[2] + w1[3];
    s2 = w2[0] + w2[1] + w2[2] + w2[3];
    float mu = s1 * (1.0f / D_);
    float var = s2 * (1.0f / D_) - mu * mu;
    float rstd = rsqrtf(var + 1e-5f);
    #pragma unroll
    for (int i = 0; i < 3; ++i) {
        int d = tid + i * 256;
        float v = (xv[i] - mu) * rstd * g[d] + beta[d];
        out[(size_t)r * D_ + d] = v;
        out_bf[(size_t)r * D_ + d] = __float2bfloat16(v);
    }
}

// ---------------- log-softmax fallback (f32 logits in place) ----------------
__global__ __launch_bounds__(256) void lsm_k(float* __restrict__ lp) {
    const int r = blockIdx.x;
    const int tid = threadIdx.x;
    const int wid = tid >> 6, lane = tid & 63;
    __shared__ float wm[4], wl[4];
    float* row = lp + (size_t)r * V_;
    float mt = -1e30f, lt = 0.f;
    for (int i = tid * 4; i < V_; i += 1024) {
        float4 v = *(const float4*)&row[i];
        float c = fmaxf(fmaxf(v.x, v.y), fmaxf(v.z, v.w));
        if (c > mt) { lt *= __expf(mt - c); mt = c; }
        lt += __expf(v.x - mt) + __expf(v.y - mt) + __expf(v.z - mt) + __expf(v.w - mt);
    }
    #pragma unroll
    for (int off = 1; off <= 32; off <<= 1) {
        float m2 = __shfl_xor(mt, off), l2 = __shfl_xor(lt, off);
        float M = fmaxf(mt, m2);
        lt = lt * __expf(mt - M) + l2 * __expf(m2 - M);
        mt = M;
    }
    if (lane == 0) { wm[wid] = mt; wl[wid] = lt; }
    __syncthreads();
    float M4 = fmaxf(fmaxf(wm[0], wm[1]), fmaxf(wm[2], wm[3]));
    float L4 = wl[0] * __expf(wm[0] - M4) + wl[1] * __expf(wm[1] - M4)
             + wl[2] * __expf(wm[2] - M4) + wl[3] * __expf(wm[3] - M4);
    float sub = M4 + __logf(L4);
    for (int i = tid * 4; i < V_; i += 1024) {
        float4 v = *(const float4*)&row[i];
        v.x -= sub; v.y -= sub; v.z -= sub; v.w -= sub;
        *(float4*)&row[i] = v;
    }
}

// ---------------- log-softmax from bf16 logits, expanding in place to f32 ----------------
// Row r's bf16 logits occupy the FRONT HALF of row r's f32 slot range (ldcb = 2V).
// Descending-chunk in-place expansion; tail chunk predicated (V % 2048 != 0).
// Output f32 writes are non-temporal.
__global__ __launch_bounds__(256) void lsmx_k(float* __restrict__ lp) {
    const int r = blockIdx.x;
    const int tid = threadIdx.x;
    const int wid = tid >> 6, lane = tid & 63;
    __shared__ float wm[4], wl[4];
    float* row = lp + (size_t)r * V_;
    const __hip_bfloat16* brow = (const __hip_bfloat16*)row;

    float mt = -1e30f, lt = 0.f;
    for (int i = tid * 8; i < V_; i += 2048) {
        short8 v = *(const short8*)&brow[i];
        #pragma unroll
        for (int j = 0; j < 8; ++j) {
            float f = b2f((unsigned short)v[j]);
            if (f > mt) { lt *= __expf(mt - f); mt = f; }
            lt += __expf(f - mt);
        }
    }
    #pragma unroll
    for (int off = 1; off <= 32; off <<= 1) {
        float m2 = __shfl_xor(mt, off), l2 = __shfl_xor(lt, off);
        float M = fmaxf(mt, m2);
        lt = lt * __expf(mt - M) + l2 * __expf(m2 - M);
        mt = M;
    }
    if (lane == 0) { wm[wid] = mt; wl[wid] = lt; }
    __syncthreads();
    float M4 = fmaxf(fmaxf(wm[0], wm[1]), fmaxf(wm[2], wm[3]));
    float L4 = wl[0] * __expf(wm[0] - M4) + wl[1] * __expf(wm[1] - M4)
             + wl[2] * __expf(wm[2] - M4) + wl[3] * __expf(wm[3] - M4);
    float sub = M4 + __logf(L4);

    for (int ci = 15; ci >= 0; --ci) {
        const int c = ci * 2048 + tid * 8;
        const bool act = (c < V_);            // tail guard: V not a multiple of 2048
        short8 v;
        if (act) v = *(const short8*)&brow[c];
        __syncthreads();                      // all reads of this chunk done before writes
        if (act) {
            f32x4 o0, o1;
            o0[0] = b2f((unsigned short)v[0]) - sub;
            o0[1] = b2f((unsigned short)v[1]) - sub;
            o0[2] = b2f((unsigned short)v[2]) - sub;
            o0[3] = b2f((unsigned short)v[3]) - sub;
            o1[0] = b2f((unsigned short)v[4]) - sub;
            o1[1] = b2f((unsigned short)v[5]) - sub;
            o1[2] = b2f((unsigned short)v[6]) - sub;
            o1[3] = b2f((unsigned short)v[7]) - sub;
            __builtin_nontemporal_store(o0, (f32x4*)&row[c]);
            __builtin_nontemporal_store(o1, (f32x4*)&row[c + 4]);
        }
    }
}

extern "C" void kernel_launch(void* const* d_in, const int* in_sizes, int n_in,
                              void* d_out, int out_size, void* d_ws, size_t ws_size,
                              hipStream_t stream) {
    const int*   x    = (const int*)  d_in[0];
    const float* tok  = (const float*)d_in[1];
    const float* pos  = (const float*)d_in[2];
    const float* Wq   = (const float*)d_in[3];
    const float* bq   = (const float*)d_in[4];
    const float* Wk   = (const float*)d_in[5];
    const float* bk   = (const float*)d_in[6];
    const float* Wv   = (const float*)d_in[7];
    const float* bv   = (const float*)d_in[8];
    const float* Wo   = (const float*)d_in[9];
    const float* bo   = (const float*)d_in[10];
    const float* ln1g = (const float*)d_in[11];
    const float* ln1b = (const float*)d_in[12];
    const float* W1   = (const float*)d_in[13];
    const float* b1   = (const float*)d_in[14];
    const float* W2   = (const float*)d_in[15];
    const float* b2   = (const float*)d_in[16];
    const float* ln2g = (const float*)d_in[17];
    const float* ln2b = (const float*)d_in[18];
    const float* Wf   = (const float*)d_in[19];
    const float* bff  = (const float*)d_in[20];

    float* out = (float*)d_out;
    const size_t HS = (size_t)BS_ * D_;              // 1,572,864

    // f32-slot layout inside logits scratch region [0, BS_*V_):
    __hip_bfloat16* qkv_bf = (__hip_bfloat16*)out;               // BS*2304 bf16
    __hip_bfloat16* vT     = (__hip_bfloat16*)(out + 2359296);   // BS*768 bf16
    __hip_bfloat16* att_bf = (__hip_bfloat16*)(out + 4718592);
    float* tmp   = out + 5505024;
    float* h1    = out + 7077888;
    __hip_bfloat16* h1_bf  = (__hip_bfloat16*)(out + 8650752);
    __hip_bfloat16* ff_bf  = (__hip_bfloat16*)(out + 9437184);
    __hip_bfloat16* h_bf   = (__hip_bfloat16*)(out + 12582912);
    __hip_bfloat16* Wqkv_t = (__hip_bfloat16*)(out + 13369344);  // 6 x [2304][768]
    __hip_bfloat16* Wo_t   = (__hip_bfloat16*)(out + 18677760);  // 6 x [768][768]
    __hip_bfloat16* W1_t   = (__hip_bfloat16*)(out + 20447232);  // 6 x [3072][768]
    __hip_bfloat16* W2_t   = (__hip_bfloat16*)(out + 27525120);  // 6 x [768][3072]
    float* bqkv  = out + 34603008;                   // 6 x 2304
    float* h     = out + (size_t)BS_ * V_;           // tail: hset output

    const bool ws_ok = ws_size >= 52297728ULL;       // Wf_t (49.15MB) + hbf (3.15MB)
    __hip_bfloat16* Wf_t   = (__hip_bfloat16*)d_ws;              // [32000][768]
    __hip_bfloat16* hbf_ws = (__hip_bfloat16*)((char*)d_ws + 49152000);

    // ---- weight transpose/convert pre-pass ----
    const size_t DD = (size_t)D_ * D_, DF = (size_t)D_ * F_;
    const size_t QKVL = (size_t)NQKV_ * D_;
    qkvt_k<<<dim3(D_/32, D_/32, 3 * L_), 256, 0, stream>>>(Wq, Wk, Wv, Wqkv_t);
    transp_k<<<dim3(D_/32, D_/32, L_), 256, 0, stream>>>(Wo, DD, Wo_t, DD,   D_, D_);
    transp_k<<<dim3(F_/32, D_/32, L_), 256, 0, stream>>>(W1, DF, W1_t, DF,   F_, D_);
    transp_k<<<dim3(D_/32, F_/32, L_), 256, 0, stream>>>(W2, DF, W2_t, DF,   D_, F_);
    bcat_k<<<L_, 256, 0, stream>>>(bq, bk, bv, bqkv);
    if (ws_ok)
        transp_k<<<dim3(V_/32, D_/32, 1), 256, 0, stream>>>(Wf, 0, Wf_t, 0, V_, D_);

    embed_k<<<BS_, 256, 0, stream>>>(x, tok, pos, h, h_bf);

    const dim3 gQKV(NQKV_/128, BS_/64);    // (18, 32) -> 576 blocks (BM=64)
    const dim3 gFF1(F_/128,    BS_/64);    // (24, 32) -> 768 blocks (BM=64)
    const dim3 gOUT64(D_/64,   BS_/64);    // (12, 32) -> 384 blocks
    const dim3 gA(S_/64, B_*H_);           // (16, 24)
    for (int i = 0; i < L_; ++i) {
        mgemm_k<64,128,0,false,true,false,false,true,false,false><<<gQKV, 256, 0, stream>>>(
            h_bf, Wqkv_t + (size_t)i * QKVL, bqkv + (size_t)i * NQKV_, nullptr, qkv_bf, vT, nullptr, BS_, NQKV_, D_, NQKV_);
        fattn_k<<<gA, 256, 0, stream>>>(qkv_bf, vT, att_bf);
        // Wo GEMM with fused residual: tmp = att@Wo + bo + h
        mgemm_k<64,64,0,true,false,false,false,false,false,true><<<gOUT64, 256, 0, stream>>>(
            att_bf, Wo_t + (size_t)i * DD, bo + (size_t)i * D_, tmp, nullptr, nullptr, h, BS_, D_, D_, D_);
        addln_k<<<BS_, 256, 0, stream>>>(tmp, ln1g + (size_t)i * D_, ln1b + (size_t)i * D_, h1, h1_bf);
        mgemm_k<64,128,1,false,true,false,false,false,false,false><<<gFF1, 256, 0, stream>>>(
            h1_bf, W1_t + (size_t)i * DF, b1 + (size_t)i * F_, nullptr, ff_bf, nullptr, nullptr, BS_, F_, D_, F_);
        // FF2 GEMM with fused residual: tmp = ff@W2 + b2 + h1
        mgemm_k<64,64,0,true,false,false,false,false,false,true><<<gOUT64, 256, 0, stream>>>(
            ff_bf, W2_t + (size_t)i * DF, b2 + (size_t)i * D_, tmp, nullptr, nullptr, h1, BS_, D_, F_, D_);
        // last layer's bf16 hset goes straight to the logits-GEMM input buffer (skips cvt)
        __hip_bfloat16* obf = (i == L_ - 1 && ws_ok) ? hbf_ws : h_bf;
        addln_k<<<BS_, 256, 0, stream>>>(tmp, ln2g + (size_t)i * D_, ln2b + (size_t)i * D_, h, obf);
    }

    if (ws_ok) {
        // bf16 logits parked at the front half of each output row (ldcb = 2V), NT stores;
        // then lsmx expands in place to f32 log-probs (NT output stream).
        mgemm_k<128,128,0,false,true,true,true,false,true,false><<<dim3(BS_/128, V_/128), 256, 0, stream>>>(
            hbf_ws, Wf_t, bff, nullptr, (__hip_bfloat16*)out, nullptr, nullptr, BS_, V_, D_, 2 * V_);
        lsmx_k<<<BS_, 256, 0, stream>>>(out);
    } else {
        gemm_k<<<dim3(V_/64, BS_/64), 256, 0, stream>>>(h, Wf, bff, out, BS_, V_, D_);
        lsm_k<<<BS_, 256, 0, stream>>>(out);
    }
}